// Round 8
// baseline (245.695 us; speedup 1.0000x reference)
//
#include <hip/hip_runtime.h>
#include <hip/hip_bf16.h>

// SkipGCN: out = gcn(relu(gcn(x,W1,b1)),W2,b2) + x@Ws + bs
// N=100000, E=1600000, in=165, hid=128, out=2, fp32 in/out.
//
// R8 changes vs R7 (agg1 76us was ISSUE/LATENCY-bound, not byte-bound:
// warm replays ran same dur with 0.9MB HBM traffic):
//  - agg1: 8 edges per wave-load. lane=(slot,cb); one dwordx4 instr loads
//    8 full fp8 rows (8 lanes x 16B each). ~3 VMEM per 8 edges instead of
//    ~17. Slot-fold via shfl_xor{8,16,32} before relu.
//  - agg2: wave-per-node, lane-per-edge (1 round covers 64 edges),
//    coalesced col_src; replaces 16-deep serial load chain per thread.
//  - rest unchanged from R7.

#define IND 165
#define HID 128
#define KP 192          // padded K for MFMA
#define BM 32           // rows per block (gemm1)
#define XSS2 208        // LDS row stride in bf16 (416B = 16B-aligned rows)
#define SLAB 8192
#define MAXNB 512

typedef __attribute__((ext_vector_type(8))) short short8v;
typedef __attribute__((ext_vector_type(4))) float float4v;
typedef __attribute__((ext_vector_type(2))) float float2v;

__device__ __forceinline__ unsigned short f2bf(float f) {
    unsigned u = __float_as_uint(f);
    unsigned r = (u + 0x7FFF + ((u >> 16) & 1)) >> 16;  // RNE
    return (unsigned short)r;
}
__device__ __forceinline__ float bf2f(unsigned short s) { return __uint_as_float(((unsigned)s) << 16); }

// ---- setup: w1t convert (blocks 0..95) + detect + zero bucket_len (block 96) ----
__global__ __launch_bounds__(256) void setup_kernel(const float* __restrict__ W1,
                                                    unsigned short* __restrict__ w1t,
                                                    const int* __restrict__ e32,
                                                    int* __restrict__ flag,
                                                    int* __restrict__ bucket_len, int NB) {
    int b = blockIdx.x;
    if (b < 96) {
        int t = b * 256 + threadIdx.x;          // t < 24576 = HID*KP
        int nn = t / KP, k = t - nn * KP;
        w1t[t] = (k < IND) ? f2bf(W1[k * HID + nn]) : (unsigned short)0;
    } else {
        __shared__ int nz;
        if (threadIdx.x == 0) nz = 0;
        __syncthreads();
        if (e32[2 * threadIdx.x + 1] != 0) atomicOr(&nz, 1);
        __syncthreads();
        if (threadIdx.x == 0) flag[0] = (nz == 0) ? 1 : 0;  // 1 => int64 layout
        for (int t = threadIdx.x; t < NB; t += 256) bucket_len[t] = 0;
    }
}

// ---- partition: edges -> per-bucket slabs of records (dstLow<<24 | src) ----
__global__ __launch_bounds__(256) void partition_kernel(const int* __restrict__ e32,
                                                        const int* __restrict__ flag,
                                                        int* __restrict__ bucket_len,
                                                        unsigned* __restrict__ slab,
                                                        int E, int NB) {
    __shared__ unsigned hist[MAXNB];
    __shared__ unsigned runbase[MAXNB];
    __shared__ unsigned cnt2[MAXNB];
    for (int t = threadIdx.x; t < NB; t += 256) { hist[t] = 0; cnt2[t] = 0; }
    __syncthreads();
    const int f = flag[0];
    const int base = blockIdx.x * 8192;
    unsigned rec[32];
    unsigned bk[32];
    #pragma unroll
    for (int j = 0; j < 32; ++j) {
        int e = base + j * 256 + threadIdx.x;
        if (e < E) {
            int src, dst;
            if (f) {
                int2 s2 = ((const int2*)e32)[e];
                int2 d2 = ((const int2*)e32)[E + e];
                src = s2.x; dst = d2.x;
            } else {
                src = e32[e];
                dst = e32[E + e];
            }
            unsigned b = (unsigned)dst >> 8;
            rec[j] = ((unsigned)(dst & 255) << 24) | (unsigned)src;
            bk[j] = b;
            atomicAdd(&hist[b], 1u);
        } else {
            bk[j] = 0xFFFFFFFFu;
            rec[j] = 0;
        }
    }
    __syncthreads();
    for (int t = threadIdx.x; t < NB; t += 256) {
        unsigned h = hist[t];
        runbase[t] = h ? (unsigned)atomicAdd(&bucket_len[t], (int)h) : 0u;
    }
    __syncthreads();
    #pragma unroll
    for (int j = 0; j < 32; ++j) {
        unsigned b = bk[j];
        if (b != 0xFFFFFFFFu) {
            unsigned p = runbase[b] + atomicAdd(&cnt2[b], 1u);
            if (p < SLAB) slab[(size_t)b * SLAB + p] = rec[j];
        }
    }
}

// ---- buildB: block per bucket; inline bucket-scan -> deg/dinv/row_ptr + col_src ----
__global__ __launch_bounds__(256) void buildb_kernel(const unsigned* __restrict__ slab,
                                                     const int* __restrict__ bucket_len,
                                                     int* __restrict__ row_ptr,
                                                     float* __restrict__ dinv,
                                                     int* __restrict__ col_src, int n, int NB) {
    __shared__ int qa[MAXNB], qb[MAXNB];
    const int b = blockIdx.x;
    const int t = threadIdx.x;
    for (int i = t; i < MAXNB; i += 256) qa[i] = (i < NB) ? min(bucket_len[i], SLAB) : 0;
    __syncthreads();
    int* s = qa; int* d = qb;
    for (int off = 1; off < MAXNB; off <<= 1) {
        for (int i = t; i < MAXNB; i += 256) d[i] = s[i] + ((i >= off) ? s[i - off] : 0);
        __syncthreads();
        int* tmp = s; s = d; d = tmp;
    }
    const int bb = (b == 0) ? 0 : s[b - 1];
    if (b == NB - 1 && t == 0) row_ptr[n] = s[NB - 1];
    const int len = min(bucket_len[b], SLAB);
    const unsigned* recs = slab + (size_t)b * SLAB;
    const int d0 = b << 8;
    __syncthreads();
    __shared__ unsigned deg[256];
    __shared__ unsigned cur[256];
    deg[t] = 0;
    __syncthreads();
    for (int i = t; i < len; i += 256) atomicAdd(&deg[recs[i] >> 24], 1u);
    __syncthreads();
    unsigned dv = deg[t];
    qa[t] = (int)dv;
    __syncthreads();
    s = qa; d = qb;
    for (int off = 1; off < 256; off <<= 1) {
        d[t] = s[t] + ((t >= off) ? s[t - off] : 0);
        __syncthreads();
        int* tmp = s; s = d; d = tmp;
    }
    unsigned excl = (unsigned)s[t] - dv;
    if (d0 + t < n) {
        dinv[d0 + t] = rsqrtf(1.0f + (float)dv);
        row_ptr[d0 + t] = bb + (int)excl;
    }
    cur[t] = excl;
    __syncthreads();
    for (int i = t; i < len; i += 256) {
        unsigned r = recs[i];
        unsigned p = (unsigned)bb + atomicAdd(&cur[r >> 24], 1u);
        col_src[p] = (int)(r & 0xFFFFFFu);
    }
}

// ---- MFMA gemm1: hb8(fp8 e4m3) = x @ W1, fused skip = x @ Ws + bs + b2 ----
__global__ __launch_bounds__(256, 4) void gemm1_kernel(const float* __restrict__ x,
                                                       const unsigned short* __restrict__ w1t,
                                                       const float* __restrict__ Ws,
                                                       const float* __restrict__ bs,
                                                       const float* __restrict__ b2,
                                                       unsigned char* __restrict__ hb8,
                                                       float* __restrict__ skip, int n) {
    __shared__ unsigned short xs[BM * XSS2];
    const int row0 = blockIdx.x * BM;
    const int tid = threadIdx.x;
    const int wave = tid >> 6, lane = tid & 63;
    const int l15 = lane & 15, lk = (lane >> 4) * 8;

    short8v bfr[12];
    #pragma unroll
    for (int nt2 = 0; nt2 < 2; ++nt2)
        #pragma unroll
        for (int ks = 0; ks < 6; ++ks)
            bfr[nt2 * 6 + ks] =
                *(const short8v*)(w1t + (size_t)((2 * wave + nt2) * 16 + l15) * KP + ks * 32 + lk);

    for (int t = tid; t < BM * (XSS2 - IND); t += 256) {
        int r = t / (XSS2 - IND), k = IND + (t - r * (XSS2 - IND));
        xs[r * XSS2 + k] = 0;
    }
    {
        const int rows = min(BM, n - row0);
        const int nflt = rows * IND;
        const float2* xsrc = (const float2*)(x + (size_t)row0 * IND);
        const int nf2 = nflt >> 1;
        for (int f = tid; f < nf2; f += 256) {
            float2 v = xsrc[f];
            int e0 = 2 * f;
            int r0 = e0 / IND, k0 = e0 - r0 * IND;
            xs[r0 * XSS2 + k0] = f2bf(v.x);
            int r1 = (k0 == IND - 1) ? r0 + 1 : r0;
            int k1 = (k0 == IND - 1) ? 0 : k0 + 1;
            xs[r1 * XSS2 + k1] = f2bf(v.y);
        }
        if ((nflt & 1) && tid == 0) {
            int e = nflt - 1;
            int r = e / IND, k = e - r * IND;
            xs[r * XSS2 + k] = f2bf(x[(size_t)row0 * IND + e]);
        }
    }
    __syncthreads();

    float4v acc[2][2];
    #pragma unroll
    for (int m = 0; m < 2; ++m)
        #pragma unroll
        for (int nt2 = 0; nt2 < 2; ++nt2) acc[m][nt2] = (float4v){0.f, 0.f, 0.f, 0.f};
    #pragma unroll
    for (int m = 0; m < 2; ++m) {
        const unsigned short* arow = xs + (m * 16 + l15) * XSS2;
        #pragma unroll
        for (int ks = 0; ks < 6; ++ks) {
            short8v a = *(const short8v*)(arow + ks * 32 + lk);
            acc[m][0] = __builtin_amdgcn_mfma_f32_16x16x32_bf16(a, bfr[ks], acc[m][0], 0, 0, 0);
            acc[m][1] = __builtin_amdgcn_mfma_f32_16x16x32_bf16(a, bfr[6 + ks], acc[m][1], 0, 0, 0);
        }
    }

    #pragma unroll
    for (int m = 0; m < 2; ++m) {
        int orow0 = row0 + m * 16 + (lane >> 4) * 4;
        #pragma unroll
        for (int nt2 = 0; nt2 < 2; ++nt2) {
            int col = (2 * wave + nt2) * 16 + l15;
            #pragma unroll
            for (int r = 0; r < 4; ++r) {
                int row = orow0 + r;
                int pk = __builtin_amdgcn_cvt_pk_fp8_f32(acc[m][nt2][r], 0.f, 0, false);
                if (row < n) hb8[(size_t)row * HID + col] = (unsigned char)(pk & 0xFF);
            }
        }
    }

    {
        int r = tid >> 3, j = tid & 7;
        int row = row0 + r;
        float s0 = 0.f, s1 = 0.f;
        if (row < n) {
            const float2* Wsv = (const float2*)Ws;
            const unsigned short* xr = xs + r * XSS2;
            for (int k = j; k < IND; k += 8) {
                float xv = bf2f(xr[k]);
                float2 w = Wsv[k];
                s0 = fmaf(xv, w.x, s0);
                s1 = fmaf(xv, w.y, s1);
            }
        }
        s0 += __shfl_xor(s0, 1); s0 += __shfl_xor(s0, 2); s0 += __shfl_xor(s0, 4);
        s1 += __shfl_xor(s1, 1); s1 += __shfl_xor(s1, 2); s1 += __shfl_xor(s1, 4);
        if (j == 0 && row < n)
            ((float2*)skip)[row] = make_float2(s0 + bs[0] + b2[0], s1 + bs[1] + b2[1]);
    }
}

// ---- layer-1 aggregate (fp8 h) + relu + fused h2 = relu(agg+b1) @ W2 ----
// wave per node; 8 edges per round: lane = (slot=lane>>3, cb=lane&7);
// slot s handles edge e+s, lane loads 16B of the 128B fp8 row.
__global__ __launch_bounds__(256) void agg1_kernel(const unsigned char* __restrict__ hb8,
                                                   const float* __restrict__ dinv,
                                                   const int* __restrict__ row_ptr,
                                                   const int* __restrict__ col_src,
                                                   const float* __restrict__ b1,
                                                   const float* __restrict__ W2,
                                                   float* __restrict__ h2, int n) {
    int wid = threadIdx.x >> 6, lane = threadIdx.x & 63;
    int i = blockIdx.x * 4 + wid;
    if (i >= n) return;
    const int slot = lane >> 3, cb = lane & 7;
    const float di = dinv[i];
    float acc[16];
    {   // self-loop round: all slots load row i (1 line), only slot 0 weighted
        uint4 r = *(const uint4*)(hb8 + (size_t)i * 128 + cb * 16);
        float w = (slot == 0) ? di * di : 0.f;
        #pragma unroll
        for (int q = 0; q < 4; ++q) {
            unsigned u = (q == 0) ? r.x : (q == 1) ? r.y : (q == 2) ? r.z : r.w;
            float2v flo = __builtin_amdgcn_cvt_pk_f32_fp8((int)u, false);
            float2v fhi = __builtin_amdgcn_cvt_pk_f32_fp8((int)u, true);
            acc[q * 4 + 0] = flo.x * w;
            acc[q * 4 + 1] = flo.y * w;
            acc[q * 4 + 2] = fhi.x * w;
            acc[q * 4 + 3] = fhi.y * w;
        }
    }
    const int end = row_ptr[i + 1];
    for (int e = row_ptr[i]; e < end; e += 8) {
        int myi = e + slot;
        int s = 0;
        float nrm = 0.f;
        if (myi < end) {
            s = col_src[myi];
            nrm = dinv[s] * di;
        }
        uint4 r = *(const uint4*)(hb8 + (size_t)s * 128 + cb * 16);
        #pragma unroll
        for (int q = 0; q < 4; ++q) {
            unsigned u = (q == 0) ? r.x : (q == 1) ? r.y : (q == 2) ? r.z : r.w;
            float2v flo = __builtin_amdgcn_cvt_pk_f32_fp8((int)u, false);
            float2v fhi = __builtin_amdgcn_cvt_pk_f32_fp8((int)u, true);
            acc[q * 4 + 0] = fmaf(flo.x, nrm, acc[q * 4 + 0]);
            acc[q * 4 + 1] = fmaf(flo.y, nrm, acc[q * 4 + 1]);
            acc[q * 4 + 2] = fmaf(fhi.x, nrm, acc[q * 4 + 2]);
            acc[q * 4 + 3] = fmaf(fhi.y, nrm, acc[q * 4 + 3]);
        }
    }
    // fold across slots (lane bits 3..5) BEFORE relu
    #pragma unroll
    for (int c = 0; c < 16; ++c) {
        acc[c] += __shfl_xor(acc[c], 8);
        acc[c] += __shfl_xor(acc[c], 16);
        acc[c] += __shfl_xor(acc[c], 32);
    }
    // bias + relu + W2 fold (16 channels per lane, dup x8 across slots)
    float p0 = 0.f, p1 = 0.f;
    const float2* W2v = (const float2*)W2;
    #pragma unroll
    for (int c = 0; c < 16; ++c) {
        int ch = cb * 16 + c;
        float v = fmaxf(acc[c] + b1[ch], 0.f);
        float2 w = W2v[ch];
        p0 = fmaf(v, w.x, p0);
        p1 = fmaf(v, w.y, p1);
    }
    p0 += __shfl_xor(p0, 1); p0 += __shfl_xor(p0, 2); p0 += __shfl_xor(p0, 4);
    p1 += __shfl_xor(p1, 1); p1 += __shfl_xor(p1, 2); p1 += __shfl_xor(p1, 4);
    if (lane == 0) ((float2*)h2)[i] = make_float2(p0, p1);
}

// ---- layer-2 aggregate + skip: wave per node, lane per edge ----
__global__ __launch_bounds__(256) void agg2_kernel(const float* __restrict__ h2,
                                                   const float* __restrict__ dinv,
                                                   const int* __restrict__ row_ptr,
                                                   const int* __restrict__ col_src,
                                                   const float* __restrict__ skip,
                                                   float* __restrict__ out, int n) {
    int wid = threadIdx.x >> 6, lane = threadIdx.x & 63;
    int i = blockIdx.x * 4 + wid;
    if (i >= n) return;
    float di = dinv[i];
    float a0 = 0.f, a1 = 0.f;
    const int beg = row_ptr[i], end = row_ptr[i + 1];
    for (int e = beg + lane; e < end; e += 64) {
        int s = col_src[e];
        float nrm = dinv[s] * di;
        float2 hs = ((const float2*)h2)[s];
        a0 = fmaf(hs.x, nrm, a0);
        a1 = fmaf(hs.y, nrm, a1);
    }
    #pragma unroll
    for (int off = 32; off; off >>= 1) {
        a0 += __shfl_xor(a0, off);
        a1 += __shfl_xor(a1, off);
    }
    if (lane == 0) {
        float2 self = ((const float2*)h2)[i];
        float2 sk = ((const float2*)skip)[i];
        ((float2*)out)[i] = make_float2(a0 + self.x * di * di + sk.x,
                                        a1 + self.y * di * di + sk.y);
    }
}

extern "C" void kernel_launch(void* const* d_in, const int* in_sizes, int n_in,
                              void* d_out, int out_size, void* d_ws, size_t ws_size,
                              hipStream_t stream) {
    const float* x  = (const float*)d_in[0];
    const int*   ei = (const int*)d_in[1];
    const float* W1 = (const float*)d_in[2];
    const float* b1 = (const float*)d_in[3];
    const float* W2 = (const float*)d_in[4];
    const float* b2 = (const float*)d_in[5];
    const float* Ws = (const float*)d_in[6];
    const float* bs = (const float*)d_in[7];
    float* out = (float*)d_out;

    const int n = in_sizes[0] / IND;        // 100000
    const int E = in_sizes[1] / 2;          // 1600000
    const int NB = (n + 255) >> 8;          // 391 buckets

    char* ws = (char*)d_ws;
    size_t off = 0;
    auto alloc = [&](size_t bytes) { void* p = ws + off; off += (bytes + 255) & ~(size_t)255; return p; };
    int*            flag        = (int*)alloc(256);
    int*            bucket_len  = (int*)alloc((size_t)(MAXNB + 1) * 4);
    unsigned*       slab        = (unsigned*)alloc((size_t)NB * SLAB * 4);
    int*            row_ptr     = (int*)alloc((size_t)(n + 1) * 4);
    float*          dinv        = (float*)alloc((size_t)n * 4);
    int*            col_src     = (int*)alloc((size_t)E * 4);
    unsigned char*  hb8         = (unsigned char*)alloc((size_t)n * HID);
    float*          h2          = (float*)alloc((size_t)n * 2 * 4);
    float*          skip        = (float*)alloc((size_t)n * 2 * 4);
    unsigned short* w1t         = (unsigned short*)alloc((size_t)HID * KP * 2);
    (void)ws_size;

    setup_kernel<<<97, 256, 0, stream>>>(W1, w1t, ei, flag, bucket_len, NB);
    partition_kernel<<<(E + 8191) / 8192, 256, 0, stream>>>(ei, flag, bucket_len, slab, E, NB);
    buildb_kernel<<<NB, 256, 0, stream>>>(slab, bucket_len, row_ptr, dinv, col_src, n, NB);

    gemm1_kernel<<<(n + BM - 1) / BM, 256, 0, stream>>>(x, w1t, Ws, bs, b2, hb8, skip, n);
    agg1_kernel<<<(n + 3) / 4, 256, 0, stream>>>(hb8, dinv, row_ptr, col_src, b1, W2, h2, n);
    agg2_kernel<<<(n + 3) / 4, 256, 0, stream>>>(h2, dinv, row_ptr, col_src, skip, out, n);
}

// Round 9
// 188.440 us; speedup vs baseline: 1.3038x; 1.3038x over previous
//
#include <hip/hip_runtime.h>
#include <hip/hip_bf16.h>

// SkipGCN: out = gcn(relu(gcn(x,W1,b1)),W2,b2) + x@Ws + bs
// N=100000, E=1600000, in=165, hid=128, out=2, fp32 in/out.
//
// R9 changes vs R8 (which REGRESSED agg1 76->142us: serial 3-deep chain per
// round + 32-VMEM/54-DS epilogue):
//  - enorm[e] = dinv[col_src[e]] precomputed (norm_kernel): agg chain 3->2.
//  - CSR segments padded to x4 (pads col=0/enorm=0), bucket-local fixed
//    SLAB regions, explicit int2 row2[](beg,end): col+enorm read as ONE
//    int4 + ONE float4 uniform load per 4 edges, no tail.
//  - agg1: 2 edges per gather instr (lane<32 edge e, lane>=32 edge e+1;
//    lane loads u32 = 4 fp8 ch). 4 VMEM / 4 edges, all independent.
//    Halves fold with one shfl_xor(32); compact W2 epilogue.
//  - agg2 uses enorm (no dinv gather).

#define IND 165
#define HID 128
#define KP 192
#define BM 32
#define XSS2 208
#define SLAB 8192
#define MAXNB 512

typedef __attribute__((ext_vector_type(8))) short short8v;
typedef __attribute__((ext_vector_type(4))) float float4v;
typedef __attribute__((ext_vector_type(2))) float float2v;

__device__ __forceinline__ unsigned short f2bf(float f) {
    unsigned u = __float_as_uint(f);
    unsigned r = (u + 0x7FFF + ((u >> 16) & 1)) >> 16;  // RNE
    return (unsigned short)r;
}
__device__ __forceinline__ float bf2f(unsigned short s) { return __uint_as_float(((unsigned)s) << 16); }

// ---- setup: w1t convert (blocks 0..95) + detect + zero bucket_len (block 96) ----
__global__ __launch_bounds__(256) void setup_kernel(const float* __restrict__ W1,
                                                    unsigned short* __restrict__ w1t,
                                                    const int* __restrict__ e32,
                                                    int* __restrict__ flag,
                                                    int* __restrict__ bucket_len, int NB) {
    int b = blockIdx.x;
    if (b < 96) {
        int t = b * 256 + threadIdx.x;
        int nn = t / KP, k = t - nn * KP;
        w1t[t] = (k < IND) ? f2bf(W1[k * HID + nn]) : (unsigned short)0;
    } else {
        __shared__ int nz;
        if (threadIdx.x == 0) nz = 0;
        __syncthreads();
        if (e32[2 * threadIdx.x + 1] != 0) atomicOr(&nz, 1);
        __syncthreads();
        if (threadIdx.x == 0) flag[0] = (nz == 0) ? 1 : 0;  // 1 => int64 layout
        for (int t = threadIdx.x; t < NB; t += 256) bucket_len[t] = 0;
    }
}

// ---- partition: edges -> per-bucket slabs of records (dstLow<<24 | src) ----
__global__ __launch_bounds__(256) void partition_kernel(const int* __restrict__ e32,
                                                        const int* __restrict__ flag,
                                                        int* __restrict__ bucket_len,
                                                        unsigned* __restrict__ slab,
                                                        int E, int NB) {
    __shared__ unsigned hist[MAXNB];
    __shared__ unsigned runbase[MAXNB];
    __shared__ unsigned cnt2[MAXNB];
    for (int t = threadIdx.x; t < NB; t += 256) { hist[t] = 0; cnt2[t] = 0; }
    __syncthreads();
    const int f = flag[0];
    const int base = blockIdx.x * 8192;
    unsigned rec[32];
    unsigned bk[32];
    #pragma unroll
    for (int j = 0; j < 32; ++j) {
        int e = base + j * 256 + threadIdx.x;
        if (e < E) {
            int src, dst;
            if (f) {
                int2 s2 = ((const int2*)e32)[e];
                int2 d2 = ((const int2*)e32)[E + e];
                src = s2.x; dst = d2.x;
            } else {
                src = e32[e];
                dst = e32[E + e];
            }
            unsigned b = (unsigned)dst >> 8;
            rec[j] = ((unsigned)(dst & 255) << 24) | (unsigned)src;
            bk[j] = b;
            atomicAdd(&hist[b], 1u);
        } else {
            bk[j] = 0xFFFFFFFFu;
            rec[j] = 0;
        }
    }
    __syncthreads();
    for (int t = threadIdx.x; t < NB; t += 256) {
        unsigned h = hist[t];
        runbase[t] = h ? (unsigned)atomicAdd(&bucket_len[t], (int)h) : 0u;
    }
    __syncthreads();
    #pragma unroll
    for (int j = 0; j < 32; ++j) {
        unsigned b = bk[j];
        if (b != 0xFFFFFFFFu) {
            unsigned p = runbase[b] + atomicAdd(&cnt2[b], 1u);
            if (p < SLAB) slab[(size_t)b * SLAB + p] = rec[j];
        }
    }
}

// ---- buildB: block per bucket -> dinv, row2(beg,end padded x4), col_src (+pads=-1) ----
__global__ __launch_bounds__(256) void buildb_kernel(const unsigned* __restrict__ slab,
                                                     const int* __restrict__ bucket_len,
                                                     int2* __restrict__ row2,
                                                     float* __restrict__ dinv,
                                                     int* __restrict__ col_src,
                                                     int* __restrict__ plen, int n) {
    __shared__ unsigned deg[256];
    __shared__ int qa[256], qb[256];
    __shared__ unsigned cur[256];
    const int b = blockIdx.x;
    const int t = threadIdx.x;
    const int len = min(bucket_len[b], SLAB);
    const unsigned* recs = slab + (size_t)b * SLAB;
    const int d0 = b << 8;
    const int base = b * SLAB;
    deg[t] = 0;
    __syncthreads();
    for (int i = t; i < len; i += 256) atomicAdd(&deg[recs[i] >> 24], 1u);
    __syncthreads();
    const unsigned dv = deg[t];
    const int pdv = (int)((dv + 3u) & ~3u);
    qa[t] = pdv;
    __syncthreads();
    int* s = qa; int* d = qb;
    for (int off = 1; off < 256; off <<= 1) {
        d[t] = s[t] + ((t >= off) ? s[t - off] : 0);
        __syncthreads();
        int* tmp = s; s = d; d = tmp;
    }
    const int pexcl = s[t] - pdv;
    if (d0 + t < n) {
        dinv[d0 + t] = rsqrtf(1.0f + (float)dv);
        row2[d0 + t] = make_int2(base + pexcl, base + pexcl + pdv);
    }
    if (t == 255) plen[b] = s[255];
    cur[t] = (unsigned)pexcl;
    __syncthreads();
    for (int i = t; i < len; i += 256) {
        unsigned r = recs[i];
        unsigned p = atomicAdd(&cur[r >> 24], 1u);
        if (p < (unsigned)SLAB) col_src[base + p] = (int)(r & 0xFFFFFFu);
    }
    // pad fill (disjoint from scatter region)
    for (int p = pexcl + (int)dv; p < pexcl + pdv; ++p)
        if (p < SLAB) col_src[base + p] = -1;
}

// ---- norm: enorm[e] = dinv[col_src[e]]; pads (col=-1) -> col=0, enorm=0 ----
__global__ __launch_bounds__(256) void norm_kernel(int* __restrict__ col_src,
                                                   float* __restrict__ enorm,
                                                   const float* __restrict__ dinv,
                                                   const int* __restrict__ plen) {
    const int b = blockIdx.x;
    const int L = min(plen[b], SLAB);
    const int base = b * SLAB;
    for (int i = threadIdx.x; i < L; i += 256) {
        int s = col_src[base + i];
        if (s >= 0) {
            enorm[base + i] = dinv[s];
        } else {
            enorm[base + i] = 0.f;
            col_src[base + i] = 0;
        }
    }
}

// ---- MFMA gemm1: hb8(fp8 e4m3) = x @ W1, fused skip = x @ Ws + bs + b2 ----
__global__ __launch_bounds__(256, 4) void gemm1_kernel(const float* __restrict__ x,
                                                       const unsigned short* __restrict__ w1t,
                                                       const float* __restrict__ Ws,
                                                       const float* __restrict__ bs,
                                                       const float* __restrict__ b2,
                                                       unsigned char* __restrict__ hb8,
                                                       float* __restrict__ skip, int n) {
    __shared__ unsigned short xs[BM * XSS2];
    const int row0 = blockIdx.x * BM;
    const int tid = threadIdx.x;
    const int wave = tid >> 6, lane = tid & 63;
    const int l15 = lane & 15, lk = (lane >> 4) * 8;

    short8v bfr[12];
    #pragma unroll
    for (int nt2 = 0; nt2 < 2; ++nt2)
        #pragma unroll
        for (int ks = 0; ks < 6; ++ks)
            bfr[nt2 * 6 + ks] =
                *(const short8v*)(w1t + (size_t)((2 * wave + nt2) * 16 + l15) * KP + ks * 32 + lk);

    for (int t = tid; t < BM * (XSS2 - IND); t += 256) {
        int r = t / (XSS2 - IND), k = IND + (t - r * (XSS2 - IND));
        xs[r * XSS2 + k] = 0;
    }
    {
        const int rows = min(BM, n - row0);
        const int nflt = rows * IND;
        const float2* xsrc = (const float2*)(x + (size_t)row0 * IND);
        const int nf2 = nflt >> 1;
        for (int f = tid; f < nf2; f += 256) {
            float2 v = xsrc[f];
            int e0 = 2 * f;
            int r0 = e0 / IND, k0 = e0 - r0 * IND;
            xs[r0 * XSS2 + k0] = f2bf(v.x);
            int r1 = (k0 == IND - 1) ? r0 + 1 : r0;
            int k1 = (k0 == IND - 1) ? 0 : k0 + 1;
            xs[r1 * XSS2 + k1] = f2bf(v.y);
        }
        if ((nflt & 1) && tid == 0) {
            int e = nflt - 1;
            int r = e / IND, k = e - r * IND;
            xs[r * XSS2 + k] = f2bf(x[(size_t)row0 * IND + e]);
        }
    }
    __syncthreads();

    float4v acc[2][2];
    #pragma unroll
    for (int m = 0; m < 2; ++m)
        #pragma unroll
        for (int nt2 = 0; nt2 < 2; ++nt2) acc[m][nt2] = (float4v){0.f, 0.f, 0.f, 0.f};
    #pragma unroll
    for (int m = 0; m < 2; ++m) {
        const unsigned short* arow = xs + (m * 16 + l15) * XSS2;
        #pragma unroll
        for (int ks = 0; ks < 6; ++ks) {
            short8v a = *(const short8v*)(arow + ks * 32 + lk);
            acc[m][0] = __builtin_amdgcn_mfma_f32_16x16x32_bf16(a, bfr[ks], acc[m][0], 0, 0, 0);
            acc[m][1] = __builtin_amdgcn_mfma_f32_16x16x32_bf16(a, bfr[6 + ks], acc[m][1], 0, 0, 0);
        }
    }

    #pragma unroll
    for (int m = 0; m < 2; ++m) {
        int orow0 = row0 + m * 16 + (lane >> 4) * 4;
        #pragma unroll
        for (int nt2 = 0; nt2 < 2; ++nt2) {
            int col = (2 * wave + nt2) * 16 + l15;
            #pragma unroll
            for (int r = 0; r < 4; ++r) {
                int row = orow0 + r;
                int pk = __builtin_amdgcn_cvt_pk_fp8_f32(acc[m][nt2][r], 0.f, 0, false);
                if (row < n) hb8[(size_t)row * HID + col] = (unsigned char)(pk & 0xFF);
            }
        }
    }

    {
        int r = tid >> 3, j = tid & 7;
        int row = row0 + r;
        float s0 = 0.f, s1 = 0.f;
        if (row < n) {
            const float2* Wsv = (const float2*)Ws;
            const unsigned short* xr = xs + r * XSS2;
            for (int k = j; k < IND; k += 8) {
                float xv = bf2f(xr[k]);
                float2 w = Wsv[k];
                s0 = fmaf(xv, w.x, s0);
                s1 = fmaf(xv, w.y, s1);
            }
        }
        s0 += __shfl_xor(s0, 1); s0 += __shfl_xor(s0, 2); s0 += __shfl_xor(s0, 4);
        s1 += __shfl_xor(s1, 1); s1 += __shfl_xor(s1, 2); s1 += __shfl_xor(s1, 4);
        if (j == 0 && row < n)
            ((float2*)skip)[row] = make_float2(s0 + bs[0] + b2[0], s1 + bs[1] + b2[1]);
    }
}

// ---- layer-1 aggregate (fp8 h) + relu + fused h2 = relu(agg+b1) @ W2 ----
// wave per node. Lane = (hl=lane>>5, cl=lane&31). Per 4 edges: one int4 +
// one float4 uniform load + two u32 row-gathers (each covers 2 rows).
// hl selects edge within pair; cl selects 4 channels (u32 of 4 fp8).
__global__ __launch_bounds__(256) void agg1_kernel(const unsigned char* __restrict__ hb8,
                                                   const float* __restrict__ dinv,
                                                   const int2* __restrict__ row2,
                                                   const int* __restrict__ col_src,
                                                   const float* __restrict__ enorm,
                                                   const float* __restrict__ b1,
                                                   const float* __restrict__ W2,
                                                   float* __restrict__ h2, int n) {
    int wid = threadIdx.x >> 6, lane = threadIdx.x & 63;
    int i = blockIdx.x * 4 + wid;
    if (i >= n) return;
    const int hl = lane >> 5, cl = lane & 31;
    const float di = dinv[i];
    float a0, a1, a2, a3;
    {   // self-loop (both halves load row i; upper half weighted 0)
        unsigned u = *(const unsigned*)(hb8 + (size_t)i * 128 + cl * 4);
        float w = hl ? 0.f : di * di;
        float2v lo = __builtin_amdgcn_cvt_pk_f32_fp8((int)u, false);
        float2v hi = __builtin_amdgcn_cvt_pk_f32_fp8((int)u, true);
        a0 = lo.x * w; a1 = lo.y * w; a2 = hi.x * w; a3 = hi.y * w;
    }
    const int2 be = row2[i];
    for (int e = be.x; e < be.y; e += 4) {
        int4   cs = *(const int4*)(col_src + e);
        float4 en = *(const float4*)(enorm + e);
        int   s0 = hl ? cs.y : cs.x;
        int   s1 = hl ? cs.w : cs.z;
        float n0 = (hl ? en.y : en.x) * di;
        float n1 = (hl ? en.w : en.z) * di;
        unsigned r0 = *(const unsigned*)(hb8 + (size_t)s0 * 128 + cl * 4);
        unsigned r1 = *(const unsigned*)(hb8 + (size_t)s1 * 128 + cl * 4);
        float2v l0 = __builtin_amdgcn_cvt_pk_f32_fp8((int)r0, false);
        float2v h0 = __builtin_amdgcn_cvt_pk_f32_fp8((int)r0, true);
        a0 = fmaf(l0.x, n0, a0); a1 = fmaf(l0.y, n0, a1);
        a2 = fmaf(h0.x, n0, a2); a3 = fmaf(h0.y, n0, a3);
        float2v l1 = __builtin_amdgcn_cvt_pk_f32_fp8((int)r1, false);
        float2v h1 = __builtin_amdgcn_cvt_pk_f32_fp8((int)r1, true);
        a0 = fmaf(l1.x, n1, a0); a1 = fmaf(l1.y, n1, a1);
        a2 = fmaf(h1.x, n1, a2); a3 = fmaf(h1.y, n1, a3);
    }
    // fold the two edge-halves (lane ^ 32 holds same channels)
    a0 += __shfl_xor(a0, 32);
    a1 += __shfl_xor(a1, 32);
    a2 += __shfl_xor(a2, 32);
    a3 += __shfl_xor(a3, 32);
    // bias + relu + W2 (channels 4cl..4cl+3)
    float4 bb = ((const float4*)b1)[cl];
    float v0 = fmaxf(a0 + bb.x, 0.f);
    float v1 = fmaxf(a1 + bb.y, 0.f);
    float v2 = fmaxf(a2 + bb.z, 0.f);
    float v3 = fmaxf(a3 + bb.w, 0.f);
    float4 wA = ((const float4*)W2)[2 * cl];      // W2[4cl][0..1], W2[4cl+1][0..1]
    float4 wB = ((const float4*)W2)[2 * cl + 1];  // W2[4cl+2][0..1], W2[4cl+3][0..1]
    float p0 = v0 * wA.x + v1 * wA.z + v2 * wB.x + v3 * wB.z;
    float p1 = v0 * wA.y + v1 * wA.w + v2 * wB.y + v3 * wB.w;
    p0 += __shfl_xor(p0, 1); p0 += __shfl_xor(p0, 2); p0 += __shfl_xor(p0, 4);
    p0 += __shfl_xor(p0, 8); p0 += __shfl_xor(p0, 16);
    p1 += __shfl_xor(p1, 1); p1 += __shfl_xor(p1, 2); p1 += __shfl_xor(p1, 4);
    p1 += __shfl_xor(p1, 8); p1 += __shfl_xor(p1, 16);
    if (lane == 0) ((float2*)h2)[i] = make_float2(p0, p1);
}

// ---- layer-2 aggregate + skip: wave per node, lane per edge, enorm-based ----
__global__ __launch_bounds__(256) void agg2_kernel(const float* __restrict__ h2,
                                                   const float* __restrict__ dinv,
                                                   const int2* __restrict__ row2,
                                                   const int* __restrict__ col_src,
                                                   const float* __restrict__ enorm,
                                                   const float* __restrict__ skip,
                                                   float* __restrict__ out, int n) {
    int wid = threadIdx.x >> 6, lane = threadIdx.x & 63;
    int i = blockIdx.x * 4 + wid;
    if (i >= n) return;
    float di = dinv[i];
    float a0 = 0.f, a1 = 0.f;
    const int2 be = row2[i];
    for (int e = be.x + lane; e < be.y; e += 64) {
        int s = col_src[e];
        float nrm = enorm[e] * di;      // pads: enorm=0
        float2 hs = ((const float2*)h2)[s];
        a0 = fmaf(hs.x, nrm, a0);
        a1 = fmaf(hs.y, nrm, a1);
    }
    #pragma unroll
    for (int off = 32; off; off >>= 1) {
        a0 += __shfl_xor(a0, off);
        a1 += __shfl_xor(a1, off);
    }
    if (lane == 0) {
        float2 self = ((const float2*)h2)[i];
        float2 sk = ((const float2*)skip)[i];
        ((float2*)out)[i] = make_float2(a0 + self.x * di * di + sk.x,
                                        a1 + self.y * di * di + sk.y);
    }
}

extern "C" void kernel_launch(void* const* d_in, const int* in_sizes, int n_in,
                              void* d_out, int out_size, void* d_ws, size_t ws_size,
                              hipStream_t stream) {
    const float* x  = (const float*)d_in[0];
    const int*   ei = (const int*)d_in[1];
    const float* W1 = (const float*)d_in[2];
    const float* b1 = (const float*)d_in[3];
    const float* W2 = (const float*)d_in[4];
    const float* b2 = (const float*)d_in[5];
    const float* Ws = (const float*)d_in[6];
    const float* bs = (const float*)d_in[7];
    float* out = (float*)d_out;

    const int n = in_sizes[0] / IND;        // 100000
    const int E = in_sizes[1] / 2;          // 1600000
    const int NB = (n + 255) >> 8;          // 391 buckets

    char* ws = (char*)d_ws;
    size_t off = 0;
    auto alloc = [&](size_t bytes) { void* p = ws + off; off += (bytes + 255) & ~(size_t)255; return p; };
    int*            flag        = (int*)alloc(256);
    int*            bucket_len  = (int*)alloc((size_t)(MAXNB + 1) * 4);
    int*            plen        = (int*)alloc((size_t)MAXNB * 4);
    unsigned*       slab        = (unsigned*)alloc((size_t)NB * SLAB * 4);
    int2*           row2        = (int2*)alloc((size_t)n * 8);
    float*          dinv        = (float*)alloc((size_t)n * 4);
    int*            col_src     = (int*)alloc((size_t)NB * SLAB * 4);
    float*          enorm       = (float*)alloc((size_t)NB * SLAB * 4);
    unsigned char*  hb8         = (unsigned char*)alloc((size_t)n * HID);
    float*          h2          = (float*)alloc((size_t)n * 2 * 4);
    float*          skip        = (float*)alloc((size_t)n * 2 * 4);
    unsigned short* w1t         = (unsigned short*)alloc((size_t)HID * KP * 2);
    (void)ws_size;

    setup_kernel<<<97, 256, 0, stream>>>(W1, w1t, ei, flag, bucket_len, NB);
    partition_kernel<<<(E + 8191) / 8192, 256, 0, stream>>>(ei, flag, bucket_len, slab, E, NB);
    buildb_kernel<<<NB, 256, 0, stream>>>(slab, bucket_len, row2, dinv, col_src, plen, n);
    norm_kernel<<<NB, 256, 0, stream>>>(col_src, enorm, dinv, plen);

    gemm1_kernel<<<(n + BM - 1) / BM, 256, 0, stream>>>(x, w1t, Ws, bs, b2, hb8, skip, n);
    agg1_kernel<<<(n + 3) / 4, 256, 0, stream>>>(hb8, dinv, row2, col_src, enorm, b1, W2, h2, n);
    agg2_kernel<<<(n + 3) / 4, 256, 0, stream>>>(h2, dinv, row2, col_src, enorm, skip, out, n);
}

// Round 10
// 176.763 us; speedup vs baseline: 1.3900x; 1.0661x over previous
//
#include <hip/hip_runtime.h>
#include <hip/hip_bf16.h>

// SkipGCN: out = gcn(relu(gcn(x,W1,b1)),W2,b2) + x@Ws + bs
// N=100000, E=1600000, in=165, hid=128, out=2, fp32 in/out.
//
// R10 changes vs R9 (agg1 66.7us, still latency/issue-bound: warm replays
// same dur @ 0.9MB HBM):
//  - hprime trick: hb8 stores h*dinv(src) (quantize AFTER mul -> same rel
//    err). agg = dinv(dst) * (sum hprime[src] + hprime[self]). Per-edge
//    norm load + fmul GONE; enorm + norm_kernel deleted.
//  - pads -> sentinel zero row n (gemm1 zeroes it); segments padded to x8.
//  - agg1: 4 rows per gather instr (slot=lane>>4 edge, cl=lane&15 loads
//    uint2 = 8ch). Per 8 edges: 2 int4 + 2 independent gathers.
//  - h2p = h2*dinv stored by agg1; agg2 loop = col + float2 gather + add.
//  - gemm1: epilogue scales by dinv (LDS-staged; runs after buildb).

#define IND 165
#define HID 128
#define KP 192
#define BM 32
#define XSS2 208
#define SLAB 8192
#define MAXNB 512

typedef __attribute__((ext_vector_type(8))) short short8v;
typedef __attribute__((ext_vector_type(4))) float float4v;
typedef __attribute__((ext_vector_type(2))) float float2v;

__device__ __forceinline__ unsigned short f2bf(float f) {
    unsigned u = __float_as_uint(f);
    unsigned r = (u + 0x7FFF + ((u >> 16) & 1)) >> 16;  // RNE
    return (unsigned short)r;
}
__device__ __forceinline__ float bf2f(unsigned short s) { return __uint_as_float(((unsigned)s) << 16); }

// ---- setup: w1t convert (blocks 0..95) + detect + zero bucket_len (block 96) ----
__global__ __launch_bounds__(256) void setup_kernel(const float* __restrict__ W1,
                                                    unsigned short* __restrict__ w1t,
                                                    const int* __restrict__ e32,
                                                    int* __restrict__ flag,
                                                    int* __restrict__ bucket_len, int NB) {
    int b = blockIdx.x;
    if (b < 96) {
        int t = b * 256 + threadIdx.x;
        int nn = t / KP, k = t - nn * KP;
        w1t[t] = (k < IND) ? f2bf(W1[k * HID + nn]) : (unsigned short)0;
    } else {
        __shared__ int nz;
        if (threadIdx.x == 0) nz = 0;
        __syncthreads();
        if (e32[2 * threadIdx.x + 1] != 0) atomicOr(&nz, 1);
        __syncthreads();
        if (threadIdx.x == 0) flag[0] = (nz == 0) ? 1 : 0;  // 1 => int64 layout
        for (int t = threadIdx.x; t < NB; t += 256) bucket_len[t] = 0;
    }
}

// ---- partition: edges -> per-bucket slabs of records (dstLow<<24 | src) ----
__global__ __launch_bounds__(256) void partition_kernel(const int* __restrict__ e32,
                                                        const int* __restrict__ flag,
                                                        int* __restrict__ bucket_len,
                                                        unsigned* __restrict__ slab,
                                                        int E, int NB) {
    __shared__ unsigned hist[MAXNB];
    __shared__ unsigned runbase[MAXNB];
    __shared__ unsigned cnt2[MAXNB];
    for (int t = threadIdx.x; t < NB; t += 256) { hist[t] = 0; cnt2[t] = 0; }
    __syncthreads();
    const int f = flag[0];
    const int base = blockIdx.x * 8192;
    unsigned rec[32];
    unsigned bk[32];
    #pragma unroll
    for (int j = 0; j < 32; ++j) {
        int e = base + j * 256 + threadIdx.x;
        if (e < E) {
            int src, dst;
            if (f) {
                int2 s2 = ((const int2*)e32)[e];
                int2 d2 = ((const int2*)e32)[E + e];
                src = s2.x; dst = d2.x;
            } else {
                src = e32[e];
                dst = e32[E + e];
            }
            unsigned b = (unsigned)dst >> 8;
            rec[j] = ((unsigned)(dst & 255) << 24) | (unsigned)src;
            bk[j] = b;
            atomicAdd(&hist[b], 1u);
        } else {
            bk[j] = 0xFFFFFFFFu;
            rec[j] = 0;
        }
    }
    __syncthreads();
    for (int t = threadIdx.x; t < NB; t += 256) {
        unsigned h = hist[t];
        runbase[t] = h ? (unsigned)atomicAdd(&bucket_len[t], (int)h) : 0u;
    }
    __syncthreads();
    #pragma unroll
    for (int j = 0; j < 32; ++j) {
        unsigned b = bk[j];
        if (b != 0xFFFFFFFFu) {
            unsigned p = runbase[b] + atomicAdd(&cnt2[b], 1u);
            if (p < SLAB) slab[(size_t)b * SLAB + p] = rec[j];
        }
    }
}

// ---- buildB: block per bucket -> dinv, row2(beg,end padded x8), col_src (pads=n) ----
__global__ __launch_bounds__(256) void buildb_kernel(const unsigned* __restrict__ slab,
                                                     const int* __restrict__ bucket_len,
                                                     int2* __restrict__ row2,
                                                     float* __restrict__ dinv,
                                                     int* __restrict__ col_src, int n) {
    __shared__ unsigned deg[256];
    __shared__ int qa[256], qb[256];
    __shared__ unsigned cur[256];
    const int b = blockIdx.x;
    const int t = threadIdx.x;
    const int len = min(bucket_len[b], SLAB);
    const unsigned* recs = slab + (size_t)b * SLAB;
    const int d0 = b << 8;
    const int base = b * SLAB;
    deg[t] = 0;
    __syncthreads();
    for (int i = t; i < len; i += 256) atomicAdd(&deg[recs[i] >> 24], 1u);
    __syncthreads();
    const unsigned dv = deg[t];
    const int pdv = (int)((dv + 7u) & ~7u);
    qa[t] = pdv;
    __syncthreads();
    int* s = qa; int* d = qb;
    for (int off = 1; off < 256; off <<= 1) {
        d[t] = s[t] + ((t >= off) ? s[t - off] : 0);
        __syncthreads();
        int* tmp = s; s = d; d = tmp;
    }
    int pexcl = s[t] - pdv;
    int pend = min(pexcl + pdv, SLAB);   // pathological-overflow clamp
    if (pexcl > SLAB) pexcl = SLAB;
    if (d0 + t < n) {
        dinv[d0 + t] = rsqrtf(1.0f + (float)dv);
        row2[d0 + t] = make_int2(base + pexcl, base + pend);
    }
    cur[t] = (unsigned)pexcl;
    __syncthreads();
    for (int i = t; i < len; i += 256) {
        unsigned r = recs[i];
        unsigned p = atomicAdd(&cur[r >> 24], 1u);
        if (p < (unsigned)SLAB) col_src[base + p] = (int)(r & 0xFFFFFFu);
    }
    // pad fill with sentinel n (zero row)
    for (int p = pexcl + (int)dv; p < pend; ++p)
        col_src[base + p] = n;
}

// ---- MFMA gemm1: hb8(fp8) = (x @ W1) * dinv[row], fused skip = x@Ws+bs+b2 ----
__global__ __launch_bounds__(256, 4) void gemm1_kernel(const float* __restrict__ x,
                                                       const unsigned short* __restrict__ w1t,
                                                       const float* __restrict__ Ws,
                                                       const float* __restrict__ bs,
                                                       const float* __restrict__ b2,
                                                       const float* __restrict__ dinv,
                                                       unsigned char* __restrict__ hb8,
                                                       float* __restrict__ h2p,
                                                       float* __restrict__ skip, int n) {
    __shared__ unsigned short xs[BM * XSS2];
    __shared__ float sdinv[BM];
    const int row0 = blockIdx.x * BM;
    const int tid = threadIdx.x;
    const int wave = tid >> 6, lane = tid & 63;
    const int l15 = lane & 15, lk = (lane >> 4) * 8;

    // sentinel zero row + h2p sentinel (block 0 only; disjoint region)
    if (blockIdx.x == 0) {
        if (tid < 32) ((unsigned*)(hb8 + (size_t)n * HID))[tid] = 0u;
        if (tid == 32) ((float2*)h2p)[n] = make_float2(0.f, 0.f);
    }
    if (tid < BM) sdinv[tid] = (row0 + tid < n) ? dinv[row0 + tid] : 1.f;

    short8v bfr[12];
    #pragma unroll
    for (int nt2 = 0; nt2 < 2; ++nt2)
        #pragma unroll
        for (int ks = 0; ks < 6; ++ks)
            bfr[nt2 * 6 + ks] =
                *(const short8v*)(w1t + (size_t)((2 * wave + nt2) * 16 + l15) * KP + ks * 32 + lk);

    for (int t = tid; t < BM * (XSS2 - IND); t += 256) {
        int r = t / (XSS2 - IND), k = IND + (t - r * (XSS2 - IND));
        xs[r * XSS2 + k] = 0;
    }
    {
        const int rows = min(BM, n - row0);
        const int nflt = rows * IND;
        const float2* xsrc = (const float2*)(x + (size_t)row0 * IND);
        const int nf2 = nflt >> 1;
        for (int f = tid; f < nf2; f += 256) {
            float2 v = xsrc[f];
            int e0 = 2 * f;
            int r0 = e0 / IND, k0 = e0 - r0 * IND;
            xs[r0 * XSS2 + k0] = f2bf(v.x);
            int r1 = (k0 == IND - 1) ? r0 + 1 : r0;
            int k1 = (k0 == IND - 1) ? 0 : k0 + 1;
            xs[r1 * XSS2 + k1] = f2bf(v.y);
        }
        if ((nflt & 1) && tid == 0) {
            int e = nflt - 1;
            int r = e / IND, k = e - r * IND;
            xs[r * XSS2 + k] = f2bf(x[(size_t)row0 * IND + e]);
        }
    }
    __syncthreads();

    float4v acc[2][2];
    #pragma unroll
    for (int m = 0; m < 2; ++m)
        #pragma unroll
        for (int nt2 = 0; nt2 < 2; ++nt2) acc[m][nt2] = (float4v){0.f, 0.f, 0.f, 0.f};
    #pragma unroll
    for (int m = 0; m < 2; ++m) {
        const unsigned short* arow = xs + (m * 16 + l15) * XSS2;
        #pragma unroll
        for (int ks = 0; ks < 6; ++ks) {
            short8v a = *(const short8v*)(arow + ks * 32 + lk);
            acc[m][0] = __builtin_amdgcn_mfma_f32_16x16x32_bf16(a, bfr[ks], acc[m][0], 0, 0, 0);
            acc[m][1] = __builtin_amdgcn_mfma_f32_16x16x32_bf16(a, bfr[6 + ks], acc[m][1], 0, 0, 0);
        }
    }

    // epilogue: hprime = acc * dinv[row], quantize fp8 e4m3
    #pragma unroll
    for (int m = 0; m < 2; ++m) {
        int rib0 = m * 16 + (lane >> 4) * 4;
        #pragma unroll
        for (int nt2 = 0; nt2 < 2; ++nt2) {
            int col = (2 * wave + nt2) * 16 + l15;
            #pragma unroll
            for (int r = 0; r < 4; ++r) {
                int row = row0 + rib0 + r;
                float hv = acc[m][nt2][r] * sdinv[rib0 + r];
                int pk = __builtin_amdgcn_cvt_pk_fp8_f32(hv, 0.f, 0, false);
                if (row < n) hb8[(size_t)row * HID + col] = (unsigned char)(pk & 0xFF);
            }
        }
    }

    {
        int r = tid >> 3, j = tid & 7;
        int row = row0 + r;
        float s0 = 0.f, s1 = 0.f;
        if (row < n) {
            const float2* Wsv = (const float2*)Ws;
            const unsigned short* xr = xs + r * XSS2;
            for (int k = j; k < IND; k += 8) {
                float xv = bf2f(xr[k]);
                float2 w = Wsv[k];
                s0 = fmaf(xv, w.x, s0);
                s1 = fmaf(xv, w.y, s1);
            }
        }
        s0 += __shfl_xor(s0, 1); s0 += __shfl_xor(s0, 2); s0 += __shfl_xor(s0, 4);
        s1 += __shfl_xor(s1, 1); s1 += __shfl_xor(s1, 2); s1 += __shfl_xor(s1, 4);
        if (j == 0 && row < n)
            ((float2*)skip)[row] = make_float2(s0 + bs[0] + b2[0], s1 + bs[1] + b2[1]);
    }
}

// ---- layer-1 aggregate: acc = sum hprime (+self), h1=relu(di*acc+b1),
//      h2p = (h1 @ W2) * di. Wave/node; slot=lane>>4 picks edge-of-4,
//      cl=lane&15 loads uint2 (8 fp8 ch). 8 edges/iter: 2 int4 + 2 gathers.
__global__ __launch_bounds__(256) void agg1_kernel(const unsigned char* __restrict__ hb8,
                                                   const float* __restrict__ dinv,
                                                   const int2* __restrict__ row2,
                                                   const int* __restrict__ col_src,
                                                   const float* __restrict__ b1,
                                                   const float* __restrict__ W2,
                                                   float* __restrict__ h2p, int n) {
    int wid = threadIdx.x >> 6, lane = threadIdx.x & 63;
    int i = blockIdx.x * 4 + wid;
    if (i >= n) return;
    const int slot = lane >> 4, cl = lane & 15;
    const float di = dinv[i];
    float a[8];
    {   // self (hprime[i]); only slot 0 contributes
        uint2 r = *(const uint2*)(hb8 + (size_t)i * 128 + cl * 8);
        float w = (slot == 0) ? 1.f : 0.f;
        float2v l0 = __builtin_amdgcn_cvt_pk_f32_fp8((int)r.x, false);
        float2v h0 = __builtin_amdgcn_cvt_pk_f32_fp8((int)r.x, true);
        float2v l1 = __builtin_amdgcn_cvt_pk_f32_fp8((int)r.y, false);
        float2v h1 = __builtin_amdgcn_cvt_pk_f32_fp8((int)r.y, true);
        a[0] = l0.x * w; a[1] = l0.y * w; a[2] = h0.x * w; a[3] = h0.y * w;
        a[4] = l1.x * w; a[5] = l1.y * w; a[6] = h1.x * w; a[7] = h1.y * w;
    }
    const int2 be = row2[i];
    for (int e = be.x; e < be.y; e += 8) {
        int4 c0 = *(const int4*)(col_src + e);
        int4 c1 = *(const int4*)(col_src + e + 4);
        int sx0 = (slot & 1) ? c0.y : c0.x;
        int sy0 = (slot & 1) ? c0.w : c0.z;
        int s0 = (slot & 2) ? sy0 : sx0;
        int sx1 = (slot & 1) ? c1.y : c1.x;
        int sy1 = (slot & 1) ? c1.w : c1.z;
        int s1 = (slot & 2) ? sy1 : sx1;
        uint2 r0 = *(const uint2*)(hb8 + (size_t)s0 * 128 + cl * 8);
        uint2 r1 = *(const uint2*)(hb8 + (size_t)s1 * 128 + cl * 8);
        {
            float2v l0 = __builtin_amdgcn_cvt_pk_f32_fp8((int)r0.x, false);
            float2v h0 = __builtin_amdgcn_cvt_pk_f32_fp8((int)r0.x, true);
            float2v l1 = __builtin_amdgcn_cvt_pk_f32_fp8((int)r0.y, false);
            float2v h1 = __builtin_amdgcn_cvt_pk_f32_fp8((int)r0.y, true);
            a[0] += l0.x; a[1] += l0.y; a[2] += h0.x; a[3] += h0.y;
            a[4] += l1.x; a[5] += l1.y; a[6] += h1.x; a[7] += h1.y;
        }
        {
            float2v l0 = __builtin_amdgcn_cvt_pk_f32_fp8((int)r1.x, false);
            float2v h0 = __builtin_amdgcn_cvt_pk_f32_fp8((int)r1.x, true);
            float2v l1 = __builtin_amdgcn_cvt_pk_f32_fp8((int)r1.y, false);
            float2v h1 = __builtin_amdgcn_cvt_pk_f32_fp8((int)r1.y, true);
            a[0] += l0.x; a[1] += l0.y; a[2] += h0.x; a[3] += h0.y;
            a[4] += l1.x; a[5] += l1.y; a[6] += h1.x; a[7] += h1.y;
        }
    }
    // fold slots (lane bits 4,5)
    #pragma unroll
    for (int c = 0; c < 8; ++c) {
        a[c] += __shfl_xor(a[c], 16);
        a[c] += __shfl_xor(a[c], 32);
    }
    // bias + relu + W2 (channels 8cl..8cl+7)
    float4 bA = ((const float4*)b1)[2 * cl];
    float4 bB = ((const float4*)b1)[2 * cl + 1];
    float v0 = fmaxf(fmaf(di, a[0], bA.x), 0.f);
    float v1 = fmaxf(fmaf(di, a[1], bA.y), 0.f);
    float v2 = fmaxf(fmaf(di, a[2], bA.z), 0.f);
    float v3 = fmaxf(fmaf(di, a[3], bA.w), 0.f);
    float v4 = fmaxf(fmaf(di, a[4], bB.x), 0.f);
    float v5 = fmaxf(fmaf(di, a[5], bB.y), 0.f);
    float v6 = fmaxf(fmaf(di, a[6], bB.z), 0.f);
    float v7 = fmaxf(fmaf(di, a[7], bB.w), 0.f);
    float4 wA = ((const float4*)W2)[4 * cl];      // rows 8cl,8cl+1
    float4 wB = ((const float4*)W2)[4 * cl + 1];  // rows 8cl+2,8cl+3
    float4 wC = ((const float4*)W2)[4 * cl + 2];
    float4 wD = ((const float4*)W2)[4 * cl + 3];
    float p0 = v0 * wA.x + v1 * wA.z + v2 * wB.x + v3 * wB.z
             + v4 * wC.x + v5 * wC.z + v6 * wD.x + v7 * wD.z;
    float p1 = v0 * wA.y + v1 * wA.w + v2 * wB.y + v3 * wB.w
             + v4 * wC.y + v5 * wC.w + v6 * wD.y + v7 * wD.w;
    p0 += __shfl_xor(p0, 1); p0 += __shfl_xor(p0, 2);
    p0 += __shfl_xor(p0, 4); p0 += __shfl_xor(p0, 8);
    p1 += __shfl_xor(p1, 1); p1 += __shfl_xor(p1, 2);
    p1 += __shfl_xor(p1, 4); p1 += __shfl_xor(p1, 8);
    if (lane == 0) ((float2*)h2p)[i] = make_float2(p0 * di, p1 * di);
}

// ---- layer-2 aggregate + skip: out = di*(sum h2p[src] + h2p[i]) + skip ----
__global__ __launch_bounds__(256) void agg2_kernel(const float* __restrict__ h2p,
                                                   const float* __restrict__ dinv,
                                                   const int2* __restrict__ row2,
                                                   const int* __restrict__ col_src,
                                                   const float* __restrict__ skip,
                                                   float* __restrict__ out, int n) {
    int wid = threadIdx.x >> 6, lane = threadIdx.x & 63;
    int i = blockIdx.x * 4 + wid;
    if (i >= n) return;
    float di = dinv[i];
    float a0 = 0.f, a1 = 0.f;
    const int2 be = row2[i];
    for (int e = be.x + lane; e < be.y; e += 64) {
        int s = col_src[e];
        float2 hs = ((const float2*)h2p)[s];   // pads -> sentinel zeros
        a0 += hs.x;
        a1 += hs.y;
    }
    #pragma unroll
    for (int off = 32; off; off >>= 1) {
        a0 += __shfl_xor(a0, off);
        a1 += __shfl_xor(a1, off);
    }
    if (lane == 0) {
        float2 self = ((const float2*)h2p)[i];
        float2 sk = ((const float2*)skip)[i];
        ((float2*)out)[i] = make_float2(di * (a0 + self.x) + sk.x,
                                        di * (a1 + self.y) + sk.y);
    }
}

extern "C" void kernel_launch(void* const* d_in, const int* in_sizes, int n_in,
                              void* d_out, int out_size, void* d_ws, size_t ws_size,
                              hipStream_t stream) {
    const float* x  = (const float*)d_in[0];
    const int*   ei = (const int*)d_in[1];
    const float* W1 = (const float*)d_in[2];
    const float* b1 = (const float*)d_in[3];
    const float* W2 = (const float*)d_in[4];
    const float* b2 = (const float*)d_in[5];
    const float* Ws = (const float*)d_in[6];
    const float* bs = (const float*)d_in[7];
    float* out = (float*)d_out;

    const int n = in_sizes[0] / IND;        // 100000
    const int E = in_sizes[1] / 2;          // 1600000
    const int NB = (n + 255) >> 8;          // 391 buckets

    char* ws = (char*)d_ws;
    size_t off = 0;
    auto alloc = [&](size_t bytes) { void* p = ws + off; off += (bytes + 255) & ~(size_t)255; return p; };
    int*            flag        = (int*)alloc(256);
    int*            bucket_len  = (int*)alloc((size_t)(MAXNB + 1) * 4);
    unsigned*       slab        = (unsigned*)alloc((size_t)NB * SLAB * 4);
    int2*           row2        = (int2*)alloc((size_t)n * 8);
    float*          dinv        = (float*)alloc((size_t)n * 4);
    int*            col_src     = (int*)alloc((size_t)NB * SLAB * 4);
    unsigned char*  hb8         = (unsigned char*)alloc((size_t)(n + 1) * HID);
    float*          h2p         = (float*)alloc((size_t)(n + 1) * 2 * 4);
    float*          skip        = (float*)alloc((size_t)n * 2 * 4);
    unsigned short* w1t         = (unsigned short*)alloc((size_t)HID * KP * 2);
    (void)ws_size;

    setup_kernel<<<97, 256, 0, stream>>>(W1, w1t, ei, flag, bucket_len, NB);
    partition_kernel<<<(E + 8191) / 8192, 256, 0, stream>>>(ei, flag, bucket_len, slab, E, NB);
    buildb_kernel<<<NB, 256, 0, stream>>>(slab, bucket_len, row2, dinv, col_src, n);

    gemm1_kernel<<<(n + BM - 1) / BM, 256, 0, stream>>>(x, w1t, Ws, bs, b2, dinv, hb8, h2p, skip, n);
    agg1_kernel<<<(n + 3) / 4, 256, 0, stream>>>(hb8, dinv, row2, col_src, b1, W2, h2p, n);
    agg2_kernel<<<(n + 3) / 4, 256, 0, stream>>>(h2p, dinv, row2, col_src, skip, out, n);
}

// Round 11
// 176.456 us; speedup vs baseline: 1.3924x; 1.0017x over previous
//
#include <hip/hip_runtime.h>
#include <hip/hip_bf16.h>

// SkipGCN: out = gcn(relu(gcn(x,W1,b1)),W2,b2) + x@Ws + bs
// N=100000, E=1600000, in=165, hid=128, out=2, fp32 in/out.
//
// R11 changes vs R10 (agg1 71us, stall-bound on 2-deep col->gather chain,
// only 2 gathers in flight; warm replay same dur @ ~0 HBM):
//  - agg1 edge loop manually software-pipelined (issue group k+1's int4
//    col loads + row gathers BEFORE consuming group k): 4 gathers in
//    flight per wave, VALU of group k overlaps memory of group k+1.
//  - deg-0 guard (be.x==be.y skips loop; pads/sentinel unchanged).
//  - everything else identical to R10.

#define IND 165
#define HID 128
#define KP 192
#define BM 32
#define XSS2 208
#define SLAB 8192
#define MAXNB 512

typedef __attribute__((ext_vector_type(8))) short short8v;
typedef __attribute__((ext_vector_type(4))) float float4v;
typedef __attribute__((ext_vector_type(2))) float float2v;

__device__ __forceinline__ unsigned short f2bf(float f) {
    unsigned u = __float_as_uint(f);
    unsigned r = (u + 0x7FFF + ((u >> 16) & 1)) >> 16;  // RNE
    return (unsigned short)r;
}
__device__ __forceinline__ float bf2f(unsigned short s) { return __uint_as_float(((unsigned)s) << 16); }

// ---- setup: w1t convert (blocks 0..95) + detect + zero bucket_len (block 96) ----
__global__ __launch_bounds__(256) void setup_kernel(const float* __restrict__ W1,
                                                    unsigned short* __restrict__ w1t,
                                                    const int* __restrict__ e32,
                                                    int* __restrict__ flag,
                                                    int* __restrict__ bucket_len, int NB) {
    int b = blockIdx.x;
    if (b < 96) {
        int t = b * 256 + threadIdx.x;
        int nn = t / KP, k = t - nn * KP;
        w1t[t] = (k < IND) ? f2bf(W1[k * HID + nn]) : (unsigned short)0;
    } else {
        __shared__ int nz;
        if (threadIdx.x == 0) nz = 0;
        __syncthreads();
        if (e32[2 * threadIdx.x + 1] != 0) atomicOr(&nz, 1);
        __syncthreads();
        if (threadIdx.x == 0) flag[0] = (nz == 0) ? 1 : 0;  // 1 => int64 layout
        for (int t = threadIdx.x; t < NB; t += 256) bucket_len[t] = 0;
    }
}

// ---- partition: edges -> per-bucket slabs of records (dstLow<<24 | src) ----
__global__ __launch_bounds__(256) void partition_kernel(const int* __restrict__ e32,
                                                        const int* __restrict__ flag,
                                                        int* __restrict__ bucket_len,
                                                        unsigned* __restrict__ slab,
                                                        int E, int NB) {
    __shared__ unsigned hist[MAXNB];
    __shared__ unsigned runbase[MAXNB];
    __shared__ unsigned cnt2[MAXNB];
    for (int t = threadIdx.x; t < NB; t += 256) { hist[t] = 0; cnt2[t] = 0; }
    __syncthreads();
    const int f = flag[0];
    const int base = blockIdx.x * 8192;
    unsigned rec[32];
    unsigned bk[32];
    #pragma unroll
    for (int j = 0; j < 32; ++j) {
        int e = base + j * 256 + threadIdx.x;
        if (e < E) {
            int src, dst;
            if (f) {
                int2 s2 = ((const int2*)e32)[e];
                int2 d2 = ((const int2*)e32)[E + e];
                src = s2.x; dst = d2.x;
            } else {
                src = e32[e];
                dst = e32[E + e];
            }
            unsigned b = (unsigned)dst >> 8;
            rec[j] = ((unsigned)(dst & 255) << 24) | (unsigned)src;
            bk[j] = b;
            atomicAdd(&hist[b], 1u);
        } else {
            bk[j] = 0xFFFFFFFFu;
            rec[j] = 0;
        }
    }
    __syncthreads();
    for (int t = threadIdx.x; t < NB; t += 256) {
        unsigned h = hist[t];
        runbase[t] = h ? (unsigned)atomicAdd(&bucket_len[t], (int)h) : 0u;
    }
    __syncthreads();
    #pragma unroll
    for (int j = 0; j < 32; ++j) {
        unsigned b = bk[j];
        if (b != 0xFFFFFFFFu) {
            unsigned p = runbase[b] + atomicAdd(&cnt2[b], 1u);
            if (p < SLAB) slab[(size_t)b * SLAB + p] = rec[j];
        }
    }
}

// ---- buildB: block per bucket -> dinv, row2(beg,end padded x8), col_src (pads=n) ----
__global__ __launch_bounds__(256) void buildb_kernel(const unsigned* __restrict__ slab,
                                                     const int* __restrict__ bucket_len,
                                                     int2* __restrict__ row2,
                                                     float* __restrict__ dinv,
                                                     int* __restrict__ col_src, int n) {
    __shared__ unsigned deg[256];
    __shared__ int qa[256], qb[256];
    __shared__ unsigned cur[256];
    const int b = blockIdx.x;
    const int t = threadIdx.x;
    const int len = min(bucket_len[b], SLAB);
    const unsigned* recs = slab + (size_t)b * SLAB;
    const int d0 = b << 8;
    const int base = b * SLAB;
    deg[t] = 0;
    __syncthreads();
    for (int i = t; i < len; i += 256) atomicAdd(&deg[recs[i] >> 24], 1u);
    __syncthreads();
    const unsigned dv = deg[t];
    const int pdv = (int)((dv + 7u) & ~7u);
    qa[t] = pdv;
    __syncthreads();
    int* s = qa; int* d = qb;
    for (int off = 1; off < 256; off <<= 1) {
        d[t] = s[t] + ((t >= off) ? s[t - off] : 0);
        __syncthreads();
        int* tmp = s; s = d; d = tmp;
    }
    int pexcl = s[t] - pdv;
    int pend = min(pexcl + pdv, SLAB);   // pathological-overflow clamp
    if (pexcl > SLAB) pexcl = SLAB;
    if (d0 + t < n) {
        dinv[d0 + t] = rsqrtf(1.0f + (float)dv);
        row2[d0 + t] = make_int2(base + pexcl, base + pend);
    }
    cur[t] = (unsigned)pexcl;
    __syncthreads();
    for (int i = t; i < len; i += 256) {
        unsigned r = recs[i];
        unsigned p = atomicAdd(&cur[r >> 24], 1u);
        if (p < (unsigned)SLAB) col_src[base + p] = (int)(r & 0xFFFFFFu);
    }
    // pad fill with sentinel n (zero row)
    for (int p = pexcl + (int)dv; p < pend; ++p)
        col_src[base + p] = n;
}

// ---- MFMA gemm1: hb8(fp8) = (x @ W1) * dinv[row], fused skip = x@Ws+bs+b2 ----
__global__ __launch_bounds__(256, 4) void gemm1_kernel(const float* __restrict__ x,
                                                       const unsigned short* __restrict__ w1t,
                                                       const float* __restrict__ Ws,
                                                       const float* __restrict__ bs,
                                                       const float* __restrict__ b2,
                                                       const float* __restrict__ dinv,
                                                       unsigned char* __restrict__ hb8,
                                                       float* __restrict__ h2p,
                                                       float* __restrict__ skip, int n) {
    __shared__ unsigned short xs[BM * XSS2];
    __shared__ float sdinv[BM];
    const int row0 = blockIdx.x * BM;
    const int tid = threadIdx.x;
    const int wave = tid >> 6, lane = tid & 63;
    const int l15 = lane & 15, lk = (lane >> 4) * 8;

    // sentinel zero row + h2p sentinel (block 0 only; disjoint region)
    if (blockIdx.x == 0) {
        if (tid < 32) ((unsigned*)(hb8 + (size_t)n * HID))[tid] = 0u;
        if (tid == 32) ((float2*)h2p)[n] = make_float2(0.f, 0.f);
    }
    if (tid < BM) sdinv[tid] = (row0 + tid < n) ? dinv[row0 + tid] : 1.f;

    short8v bfr[12];
    #pragma unroll
    for (int nt2 = 0; nt2 < 2; ++nt2)
        #pragma unroll
        for (int ks = 0; ks < 6; ++ks)
            bfr[nt2 * 6 + ks] =
                *(const short8v*)(w1t + (size_t)((2 * wave + nt2) * 16 + l15) * KP + ks * 32 + lk);

    for (int t = tid; t < BM * (XSS2 - IND); t += 256) {
        int r = t / (XSS2 - IND), k = IND + (t - r * (XSS2 - IND));
        xs[r * XSS2 + k] = 0;
    }
    {
        const int rows = min(BM, n - row0);
        const int nflt = rows * IND;
        const float2* xsrc = (const float2*)(x + (size_t)row0 * IND);
        const int nf2 = nflt >> 1;
        for (int f = tid; f < nf2; f += 256) {
            float2 v = xsrc[f];
            int e0 = 2 * f;
            int r0 = e0 / IND, k0 = e0 - r0 * IND;
            xs[r0 * XSS2 + k0] = f2bf(v.x);
            int r1 = (k0 == IND - 1) ? r0 + 1 : r0;
            int k1 = (k0 == IND - 1) ? 0 : k0 + 1;
            xs[r1 * XSS2 + k1] = f2bf(v.y);
        }
        if ((nflt & 1) && tid == 0) {
            int e = nflt - 1;
            int r = e / IND, k = e - r * IND;
            xs[r * XSS2 + k] = f2bf(x[(size_t)row0 * IND + e]);
        }
    }
    __syncthreads();

    float4v acc[2][2];
    #pragma unroll
    for (int m = 0; m < 2; ++m)
        #pragma unroll
        for (int nt2 = 0; nt2 < 2; ++nt2) acc[m][nt2] = (float4v){0.f, 0.f, 0.f, 0.f};
    #pragma unroll
    for (int m = 0; m < 2; ++m) {
        const unsigned short* arow = xs + (m * 16 + l15) * XSS2;
        #pragma unroll
        for (int ks = 0; ks < 6; ++ks) {
            short8v a = *(const short8v*)(arow + ks * 32 + lk);
            acc[m][0] = __builtin_amdgcn_mfma_f32_16x16x32_bf16(a, bfr[ks], acc[m][0], 0, 0, 0);
            acc[m][1] = __builtin_amdgcn_mfma_f32_16x16x32_bf16(a, bfr[6 + ks], acc[m][1], 0, 0, 0);
        }
    }

    // epilogue: hprime = acc * dinv[row], quantize fp8 e4m3
    #pragma unroll
    for (int m = 0; m < 2; ++m) {
        int rib0 = m * 16 + (lane >> 4) * 4;
        #pragma unroll
        for (int nt2 = 0; nt2 < 2; ++nt2) {
            int col = (2 * wave + nt2) * 16 + l15;
            #pragma unroll
            for (int r = 0; r < 4; ++r) {
                int row = row0 + rib0 + r;
                float hv = acc[m][nt2][r] * sdinv[rib0 + r];
                int pk = __builtin_amdgcn_cvt_pk_fp8_f32(hv, 0.f, 0, false);
                if (row < n) hb8[(size_t)row * HID + col] = (unsigned char)(pk & 0xFF);
            }
        }
    }

    {
        int r = tid >> 3, j = tid & 7;
        int row = row0 + r;
        float s0 = 0.f, s1 = 0.f;
        if (row < n) {
            const float2* Wsv = (const float2*)Ws;
            const unsigned short* xr = xs + r * XSS2;
            for (int k = j; k < IND; k += 8) {
                float xv = bf2f(xr[k]);
                float2 w = Wsv[k];
                s0 = fmaf(xv, w.x, s0);
                s1 = fmaf(xv, w.y, s1);
            }
        }
        s0 += __shfl_xor(s0, 1); s0 += __shfl_xor(s0, 2); s0 += __shfl_xor(s0, 4);
        s1 += __shfl_xor(s1, 1); s1 += __shfl_xor(s1, 2); s1 += __shfl_xor(s1, 4);
        if (j == 0 && row < n)
            ((float2*)skip)[row] = make_float2(s0 + bs[0] + b2[0], s1 + bs[1] + b2[1]);
    }
}

// ---- layer-1 aggregate, software-pipelined ----
// acc = sum hprime (+self), h1=relu(di*acc+b1), h2p=(h1@W2)*di.
// Wave/node; slot=lane>>4 picks edge-of-4, cl=lane&15 loads uint2 (8ch).
// Pipeline: issue group k+1 cols+gathers before consuming group k.
__global__ __launch_bounds__(256) void agg1_kernel(const unsigned char* __restrict__ hb8,
                                                   const float* __restrict__ dinv,
                                                   const int2* __restrict__ row2,
                                                   const int* __restrict__ col_src,
                                                   const float* __restrict__ b1,
                                                   const float* __restrict__ W2,
                                                   float* __restrict__ h2p, int n) {
    int wid = threadIdx.x >> 6, lane = threadIdx.x & 63;
    int i = blockIdx.x * 4 + wid;
    if (i >= n) return;
    const int slot = lane >> 4, cl = lane & 15;
    const float di = dinv[i];
    float a[8];
    {   // self (hprime[i]); only slot 0 contributes
        uint2 r = *(const uint2*)(hb8 + (size_t)i * 128 + cl * 8);
        float w = (slot == 0) ? 1.f : 0.f;
        float2v l0 = __builtin_amdgcn_cvt_pk_f32_fp8((int)r.x, false);
        float2v h0 = __builtin_amdgcn_cvt_pk_f32_fp8((int)r.x, true);
        float2v l1 = __builtin_amdgcn_cvt_pk_f32_fp8((int)r.y, false);
        float2v h1 = __builtin_amdgcn_cvt_pk_f32_fp8((int)r.y, true);
        a[0] = l0.x * w; a[1] = l0.y * w; a[2] = h0.x * w; a[3] = h0.y * w;
        a[4] = l1.x * w; a[5] = l1.y * w; a[6] = h1.x * w; a[7] = h1.y * w;
    }
    const int2 be = row2[i];
    if (be.x < be.y) {
        // prologue: group 0 cols + gathers
        int4 c0 = *(const int4*)(col_src + be.x);
        int4 c1 = *(const int4*)(col_src + be.x + 4);
        int sx0 = (slot & 1) ? c0.y : c0.x;
        int sy0 = (slot & 1) ? c0.w : c0.z;
        int s0  = (slot & 2) ? sy0 : sx0;
        int sx1 = (slot & 1) ? c1.y : c1.x;
        int sy1 = (slot & 1) ? c1.w : c1.z;
        int s1  = (slot & 2) ? sy1 : sx1;
        uint2 r0 = *(const uint2*)(hb8 + (size_t)s0 * 128 + cl * 8);
        uint2 r1 = *(const uint2*)(hb8 + (size_t)s1 * 128 + cl * 8);
        for (int e = be.x + 8; e < be.y; e += 8) {
            // issue group k+1
            int4 n0 = *(const int4*)(col_src + e);
            int4 n1 = *(const int4*)(col_src + e + 4);
            int tx0 = (slot & 1) ? n0.y : n0.x;
            int ty0 = (slot & 1) ? n0.w : n0.z;
            int t0  = (slot & 2) ? ty0 : tx0;
            int tx1 = (slot & 1) ? n1.y : n1.x;
            int ty1 = (slot & 1) ? n1.w : n1.z;
            int t1  = (slot & 2) ? ty1 : tx1;
            uint2 q0 = *(const uint2*)(hb8 + (size_t)t0 * 128 + cl * 8);
            uint2 q1 = *(const uint2*)(hb8 + (size_t)t1 * 128 + cl * 8);
            // consume group k
            {
                float2v l0 = __builtin_amdgcn_cvt_pk_f32_fp8((int)r0.x, false);
                float2v h0 = __builtin_amdgcn_cvt_pk_f32_fp8((int)r0.x, true);
                float2v l1 = __builtin_amdgcn_cvt_pk_f32_fp8((int)r0.y, false);
                float2v h1 = __builtin_amdgcn_cvt_pk_f32_fp8((int)r0.y, true);
                a[0] += l0.x; a[1] += l0.y; a[2] += h0.x; a[3] += h0.y;
                a[4] += l1.x; a[5] += l1.y; a[6] += h1.x; a[7] += h1.y;
            }
            {
                float2v l0 = __builtin_amdgcn_cvt_pk_f32_fp8((int)r1.x, false);
                float2v h0 = __builtin_amdgcn_cvt_pk_f32_fp8((int)r1.x, true);
                float2v l1 = __builtin_amdgcn_cvt_pk_f32_fp8((int)r1.y, false);
                float2v h1 = __builtin_amdgcn_cvt_pk_f32_fp8((int)r1.y, true);
                a[0] += l0.x; a[1] += l0.y; a[2] += h0.x; a[3] += h0.y;
                a[4] += l1.x; a[5] += l1.y; a[6] += h1.x; a[7] += h1.y;
            }
            r0 = q0; r1 = q1;
        }
        // epilogue consume: last group
        {
            float2v l0 = __builtin_amdgcn_cvt_pk_f32_fp8((int)r0.x, false);
            float2v h0 = __builtin_amdgcn_cvt_pk_f32_fp8((int)r0.x, true);
            float2v l1 = __builtin_amdgcn_cvt_pk_f32_fp8((int)r0.y, false);
            float2v h1 = __builtin_amdgcn_cvt_pk_f32_fp8((int)r0.y, true);
            a[0] += l0.x; a[1] += l0.y; a[2] += h0.x; a[3] += h0.y;
            a[4] += l1.x; a[5] += l1.y; a[6] += h1.x; a[7] += h1.y;
        }
        {
            float2v l0 = __builtin_amdgcn_cvt_pk_f32_fp8((int)r1.x, false);
            float2v h0 = __builtin_amdgcn_cvt_pk_f32_fp8((int)r1.x, true);
            float2v l1 = __builtin_amdgcn_cvt_pk_f32_fp8((int)r1.y, false);
            float2v h1 = __builtin_amdgcn_cvt_pk_f32_fp8((int)r1.y, true);
            a[0] += l0.x; a[1] += l0.y; a[2] += h0.x; a[3] += h0.y;
            a[4] += l1.x; a[5] += l1.y; a[6] += h1.x; a[7] += h1.y;
        }
    }
    // fold slots (lane bits 4,5)
    #pragma unroll
    for (int c = 0; c < 8; ++c) {
        a[c] += __shfl_xor(a[c], 16);
        a[c] += __shfl_xor(a[c], 32);
    }
    // bias + relu + W2 (channels 8cl..8cl+7)
    float4 bA = ((const float4*)b1)[2 * cl];
    float4 bB = ((const float4*)b1)[2 * cl + 1];
    float v0 = fmaxf(fmaf(di, a[0], bA.x), 0.f);
    float v1 = fmaxf(fmaf(di, a[1], bA.y), 0.f);
    float v2 = fmaxf(fmaf(di, a[2], bA.z), 0.f);
    float v3 = fmaxf(fmaf(di, a[3], bA.w), 0.f);
    float v4 = fmaxf(fmaf(di, a[4], bB.x), 0.f);
    float v5 = fmaxf(fmaf(di, a[5], bB.y), 0.f);
    float v6 = fmaxf(fmaf(di, a[6], bB.z), 0.f);
    float v7 = fmaxf(fmaf(di, a[7], bB.w), 0.f);
    float4 wA = ((const float4*)W2)[4 * cl];      // rows 8cl,8cl+1
    float4 wB = ((const float4*)W2)[4 * cl + 1];  // rows 8cl+2,8cl+3
    float4 wC = ((const float4*)W2)[4 * cl + 2];
    float4 wD = ((const float4*)W2)[4 * cl + 3];
    float p0 = v0 * wA.x + v1 * wA.z + v2 * wB.x + v3 * wB.z
             + v4 * wC.x + v5 * wC.z + v6 * wD.x + v7 * wD.z;
    float p1 = v0 * wA.y + v1 * wA.w + v2 * wB.y + v3 * wB.w
             + v4 * wC.y + v5 * wC.w + v6 * wD.y + v7 * wD.w;
    p0 += __shfl_xor(p0, 1); p0 += __shfl_xor(p0, 2);
    p0 += __shfl_xor(p0, 4); p0 += __shfl_xor(p0, 8);
    p1 += __shfl_xor(p1, 1); p1 += __shfl_xor(p1, 2);
    p1 += __shfl_xor(p1, 4); p1 += __shfl_xor(p1, 8);
    if (lane == 0) ((float2*)h2p)[i] = make_float2(p0 * di, p1 * di);
}

// ---- layer-2 aggregate + skip: out = di*(sum h2p[src] + h2p[i]) + skip ----
__global__ __launch_bounds__(256) void agg2_kernel(const float* __restrict__ h2p,
                                                   const float* __restrict__ dinv,
                                                   const int2* __restrict__ row2,
                                                   const int* __restrict__ col_src,
                                                   const float* __restrict__ skip,
                                                   float* __restrict__ out, int n) {
    int wid = threadIdx.x >> 6, lane = threadIdx.x & 63;
    int i = blockIdx.x * 4 + wid;
    if (i >= n) return;
    float di = dinv[i];
    float a0 = 0.f, a1 = 0.f;
    const int2 be = row2[i];
    for (int e = be.x + lane; e < be.y; e += 64) {
        int s = col_src[e];
        float2 hs = ((const float2*)h2p)[s];   // pads -> sentinel zeros
        a0 += hs.x;
        a1 += hs.y;
    }
    #pragma unroll
    for (int off = 32; off; off >>= 1) {
        a0 += __shfl_xor(a0, off);
        a1 += __shfl_xor(a1, off);
    }
    if (lane == 0) {
        float2 self = ((const float2*)h2p)[i];
        float2 sk = ((const float2*)skip)[i];
        ((float2*)out)[i] = make_float2(di * (a0 + self.x) + sk.x,
                                        di * (a1 + self.y) + sk.y);
    }
}

extern "C" void kernel_launch(void* const* d_in, const int* in_sizes, int n_in,
                              void* d_out, int out_size, void* d_ws, size_t ws_size,
                              hipStream_t stream) {
    const float* x  = (const float*)d_in[0];
    const int*   ei = (const int*)d_in[1];
    const float* W1 = (const float*)d_in[2];
    const float* b1 = (const float*)d_in[3];
    const float* W2 = (const float*)d_in[4];
    const float* b2 = (const float*)d_in[5];
    const float* Ws = (const float*)d_in[6];
    const float* bs = (const float*)d_in[7];
    float* out = (float*)d_out;

    const int n = in_sizes[0] / IND;        // 100000
    const int E = in_sizes[1] / 2;          // 1600000
    const int NB = (n + 255) >> 8;          // 391 buckets

    char* ws = (char*)d_ws;
    size_t off = 0;
    auto alloc = [&](size_t bytes) { void* p = ws + off; off += (bytes + 255) & ~(size_t)255; return p; };
    int*            flag        = (int*)alloc(256);
    int*            bucket_len  = (int*)alloc((size_t)(MAXNB + 1) * 4);
    unsigned*       slab        = (unsigned*)alloc((size_t)NB * SLAB * 4);
    int2*           row2        = (int2*)alloc((size_t)n * 8);
    float*          dinv        = (float*)alloc((size_t)n * 4);
    int*            col_src     = (int*)alloc((size_t)NB * SLAB * 4);
    unsigned char*  hb8         = (unsigned char*)alloc((size_t)(n + 1) * HID);
    float*          h2p         = (float*)alloc((size_t)(n + 1) * 2 * 4);
    float*          skip        = (float*)alloc((size_t)n * 2 * 4);
    unsigned short* w1t         = (unsigned short*)alloc((size_t)HID * KP * 2);
    (void)ws_size;

    setup_kernel<<<97, 256, 0, stream>>>(W1, w1t, ei, flag, bucket_len, NB);
    partition_kernel<<<(E + 8191) / 8192, 256, 0, stream>>>(ei, flag, bucket_len, slab, E, NB);
    buildb_kernel<<<NB, 256, 0, stream>>>(slab, bucket_len, row2, dinv, col_src, n);

    gemm1_kernel<<<(n + BM - 1) / BM, 256, 0, stream>>>(x, w1t, Ws, bs, b2, dinv, hb8, h2p, skip, n);
    agg1_kernel<<<(n + 3) / 4, 256, 0, stream>>>(hb8, dinv, row2, col_src, b1, W2, h2p, n);
    agg2_kernel<<<(n + 3) / 4, 256, 0, stream>>>(h2p, dinv, row2, col_src, skip, out, n);
}

// Round 12
// 167.525 us; speedup vs baseline: 1.4666x; 1.0533x over previous
//
#include <hip/hip_runtime.h>
#include <hip/hip_bf16.h>

// SkipGCN: out = gcn(relu(gcn(x,W1,b1)),W2,b2) + x@Ws + bs
// N=100000, E=1600000, in=165, hid=128, out=2, fp32 in/out.
//
// R12 changes vs R11 (agg1 70us NULL on sw-pipelining; 4 structures
// converge ~70us; discriminating instruction-diet experiment):
//  - agg1: readfirstlane(beg/end) -> col_src+e provably uniform -> compiler
//    emits s_load_dwordx4 (SMEM pipe) for cols instead of VMEM gathers;
//    frees VMEM queue for row gathers. Manual pipeline dropped (was null).
//  - agg1: packed accumulation (float2v += float2v -> v_pk_add_f32),
//    loop VALU -30%.
//  - agg2: readfirstlane bounds.
//  - everything else identical to R11.

#define IND 165
#define HID 128
#define KP 192
#define BM 32
#define XSS2 208
#define SLAB 8192
#define MAXNB 512

typedef __attribute__((ext_vector_type(8))) short short8v;
typedef __attribute__((ext_vector_type(4))) float float4v;
typedef __attribute__((ext_vector_type(2))) float float2v;

__device__ __forceinline__ unsigned short f2bf(float f) {
    unsigned u = __float_as_uint(f);
    unsigned r = (u + 0x7FFF + ((u >> 16) & 1)) >> 16;  // RNE
    return (unsigned short)r;
}
__device__ __forceinline__ float bf2f(unsigned short s) { return __uint_as_float(((unsigned)s) << 16); }

// ---- setup: w1t convert (blocks 0..95) + detect + zero bucket_len (block 96) ----
__global__ __launch_bounds__(256) void setup_kernel(const float* __restrict__ W1,
                                                    unsigned short* __restrict__ w1t,
                                                    const int* __restrict__ e32,
                                                    int* __restrict__ flag,
                                                    int* __restrict__ bucket_len, int NB) {
    int b = blockIdx.x;
    if (b < 96) {
        int t = b * 256 + threadIdx.x;
        int nn = t / KP, k = t - nn * KP;
        w1t[t] = (k < IND) ? f2bf(W1[k * HID + nn]) : (unsigned short)0;
    } else {
        __shared__ int nz;
        if (threadIdx.x == 0) nz = 0;
        __syncthreads();
        if (e32[2 * threadIdx.x + 1] != 0) atomicOr(&nz, 1);
        __syncthreads();
        if (threadIdx.x == 0) flag[0] = (nz == 0) ? 1 : 0;  // 1 => int64 layout
        for (int t = threadIdx.x; t < NB; t += 256) bucket_len[t] = 0;
    }
}

// ---- partition: edges -> per-bucket slabs of records (dstLow<<24 | src) ----
__global__ __launch_bounds__(256) void partition_kernel(const int* __restrict__ e32,
                                                        const int* __restrict__ flag,
                                                        int* __restrict__ bucket_len,
                                                        unsigned* __restrict__ slab,
                                                        int E, int NB) {
    __shared__ unsigned hist[MAXNB];
    __shared__ unsigned runbase[MAXNB];
    __shared__ unsigned cnt2[MAXNB];
    for (int t = threadIdx.x; t < NB; t += 256) { hist[t] = 0; cnt2[t] = 0; }
    __syncthreads();
    const int f = flag[0];
    const int base = blockIdx.x * 8192;
    unsigned rec[32];
    unsigned bk[32];
    #pragma unroll
    for (int j = 0; j < 32; ++j) {
        int e = base + j * 256 + threadIdx.x;
        if (e < E) {
            int src, dst;
            if (f) {
                int2 s2 = ((const int2*)e32)[e];
                int2 d2 = ((const int2*)e32)[E + e];
                src = s2.x; dst = d2.x;
            } else {
                src = e32[e];
                dst = e32[E + e];
            }
            unsigned b = (unsigned)dst >> 8;
            rec[j] = ((unsigned)(dst & 255) << 24) | (unsigned)src;
            bk[j] = b;
            atomicAdd(&hist[b], 1u);
        } else {
            bk[j] = 0xFFFFFFFFu;
            rec[j] = 0;
        }
    }
    __syncthreads();
    for (int t = threadIdx.x; t < NB; t += 256) {
        unsigned h = hist[t];
        runbase[t] = h ? (unsigned)atomicAdd(&bucket_len[t], (int)h) : 0u;
    }
    __syncthreads();
    #pragma unroll
    for (int j = 0; j < 32; ++j) {
        unsigned b = bk[j];
        if (b != 0xFFFFFFFFu) {
            unsigned p = runbase[b] + atomicAdd(&cnt2[b], 1u);
            if (p < SLAB) slab[(size_t)b * SLAB + p] = rec[j];
        }
    }
}

// ---- buildB: block per bucket -> dinv, row2(beg,end padded x8), col_src (pads=n) ----
__global__ __launch_bounds__(256) void buildb_kernel(const unsigned* __restrict__ slab,
                                                     const int* __restrict__ bucket_len,
                                                     int2* __restrict__ row2,
                                                     float* __restrict__ dinv,
                                                     int* __restrict__ col_src, int n) {
    __shared__ unsigned deg[256];
    __shared__ int qa[256], qb[256];
    __shared__ unsigned cur[256];
    const int b = blockIdx.x;
    const int t = threadIdx.x;
    const int len = min(bucket_len[b], SLAB);
    const unsigned* recs = slab + (size_t)b * SLAB;
    const int d0 = b << 8;
    const int base = b * SLAB;
    deg[t] = 0;
    __syncthreads();
    for (int i = t; i < len; i += 256) atomicAdd(&deg[recs[i] >> 24], 1u);
    __syncthreads();
    const unsigned dv = deg[t];
    const int pdv = (int)((dv + 7u) & ~7u);
    qa[t] = pdv;
    __syncthreads();
    int* s = qa; int* d = qb;
    for (int off = 1; off < 256; off <<= 1) {
        d[t] = s[t] + ((t >= off) ? s[t - off] : 0);
        __syncthreads();
        int* tmp = s; s = d; d = tmp;
    }
    int pexcl = s[t] - pdv;
    int pend = min(pexcl + pdv, SLAB);   // pathological-overflow clamp
    if (pexcl > SLAB) pexcl = SLAB;
    if (d0 + t < n) {
        dinv[d0 + t] = rsqrtf(1.0f + (float)dv);
        row2[d0 + t] = make_int2(base + pexcl, base + pend);
    }
    cur[t] = (unsigned)pexcl;
    __syncthreads();
    for (int i = t; i < len; i += 256) {
        unsigned r = recs[i];
        unsigned p = atomicAdd(&cur[r >> 24], 1u);
        if (p < (unsigned)SLAB) col_src[base + p] = (int)(r & 0xFFFFFFu);
    }
    // pad fill with sentinel n (zero row)
    for (int p = pexcl + (int)dv; p < pend; ++p)
        col_src[base + p] = n;
}

// ---- MFMA gemm1: hb8(fp8) = (x @ W1) * dinv[row], fused skip = x@Ws+bs+b2 ----
__global__ __launch_bounds__(256, 4) void gemm1_kernel(const float* __restrict__ x,
                                                       const unsigned short* __restrict__ w1t,
                                                       const float* __restrict__ Ws,
                                                       const float* __restrict__ bs,
                                                       const float* __restrict__ b2,
                                                       const float* __restrict__ dinv,
                                                       unsigned char* __restrict__ hb8,
                                                       float* __restrict__ h2p,
                                                       float* __restrict__ skip, int n) {
    __shared__ unsigned short xs[BM * XSS2];
    __shared__ float sdinv[BM];
    const int row0 = blockIdx.x * BM;
    const int tid = threadIdx.x;
    const int wave = tid >> 6, lane = tid & 63;
    const int l15 = lane & 15, lk = (lane >> 4) * 8;

    // sentinel zero row + h2p sentinel (block 0 only; disjoint region)
    if (blockIdx.x == 0) {
        if (tid < 32) ((unsigned*)(hb8 + (size_t)n * HID))[tid] = 0u;
        if (tid == 32) ((float2*)h2p)[n] = make_float2(0.f, 0.f);
    }
    if (tid < BM) sdinv[tid] = (row0 + tid < n) ? dinv[row0 + tid] : 1.f;

    short8v bfr[12];
    #pragma unroll
    for (int nt2 = 0; nt2 < 2; ++nt2)
        #pragma unroll
        for (int ks = 0; ks < 6; ++ks)
            bfr[nt2 * 6 + ks] =
                *(const short8v*)(w1t + (size_t)((2 * wave + nt2) * 16 + l15) * KP + ks * 32 + lk);

    for (int t = tid; t < BM * (XSS2 - IND); t += 256) {
        int r = t / (XSS2 - IND), k = IND + (t - r * (XSS2 - IND));
        xs[r * XSS2 + k] = 0;
    }
    {
        const int rows = min(BM, n - row0);
        const int nflt = rows * IND;
        const float2* xsrc = (const float2*)(x + (size_t)row0 * IND);
        const int nf2 = nflt >> 1;
        for (int f = tid; f < nf2; f += 256) {
            float2 v = xsrc[f];
            int e0 = 2 * f;
            int r0 = e0 / IND, k0 = e0 - r0 * IND;
            xs[r0 * XSS2 + k0] = f2bf(v.x);
            int r1 = (k0 == IND - 1) ? r0 + 1 : r0;
            int k1 = (k0 == IND - 1) ? 0 : k0 + 1;
            xs[r1 * XSS2 + k1] = f2bf(v.y);
        }
        if ((nflt & 1) && tid == 0) {
            int e = nflt - 1;
            int r = e / IND, k = e - r * IND;
            xs[r * XSS2 + k] = f2bf(x[(size_t)row0 * IND + e]);
        }
    }
    __syncthreads();

    float4v acc[2][2];
    #pragma unroll
    for (int m = 0; m < 2; ++m)
        #pragma unroll
        for (int nt2 = 0; nt2 < 2; ++nt2) acc[m][nt2] = (float4v){0.f, 0.f, 0.f, 0.f};
    #pragma unroll
    for (int m = 0; m < 2; ++m) {
        const unsigned short* arow = xs + (m * 16 + l15) * XSS2;
        #pragma unroll
        for (int ks = 0; ks < 6; ++ks) {
            short8v a = *(const short8v*)(arow + ks * 32 + lk);
            acc[m][0] = __builtin_amdgcn_mfma_f32_16x16x32_bf16(a, bfr[ks], acc[m][0], 0, 0, 0);
            acc[m][1] = __builtin_amdgcn_mfma_f32_16x16x32_bf16(a, bfr[6 + ks], acc[m][1], 0, 0, 0);
        }
    }

    // epilogue: hprime = acc * dinv[row], quantize fp8 e4m3
    #pragma unroll
    for (int m = 0; m < 2; ++m) {
        int rib0 = m * 16 + (lane >> 4) * 4;
        #pragma unroll
        for (int nt2 = 0; nt2 < 2; ++nt2) {
            int col = (2 * wave + nt2) * 16 + l15;
            #pragma unroll
            for (int r = 0; r < 4; ++r) {
                int row = row0 + rib0 + r;
                float hv = acc[m][nt2][r] * sdinv[rib0 + r];
                int pk = __builtin_amdgcn_cvt_pk_fp8_f32(hv, 0.f, 0, false);
                if (row < n) hb8[(size_t)row * HID + col] = (unsigned char)(pk & 0xFF);
            }
        }
    }

    {
        int r = tid >> 3, j = tid & 7;
        int row = row0 + r;
        float s0 = 0.f, s1 = 0.f;
        if (row < n) {
            const float2* Wsv = (const float2*)Ws;
            const unsigned short* xr = xs + r * XSS2;
            for (int k = j; k < IND; k += 8) {
                float xv = bf2f(xr[k]);
                float2 w = Wsv[k];
                s0 = fmaf(xv, w.x, s0);
                s1 = fmaf(xv, w.y, s1);
            }
        }
        s0 += __shfl_xor(s0, 1); s0 += __shfl_xor(s0, 2); s0 += __shfl_xor(s0, 4);
        s1 += __shfl_xor(s1, 1); s1 += __shfl_xor(s1, 2); s1 += __shfl_xor(s1, 4);
        if (j == 0 && row < n)
            ((float2*)skip)[row] = make_float2(s0 + bs[0] + b2[0], s1 + bs[1] + b2[1]);
    }
}

// ---- layer-1 aggregate: acc = sum hprime (+self), h1=relu(di*acc+b1),
//      h2p = (h1 @ W2) * di. Wave/node; slot=lane>>4, cl=lane&15 (uint2=8ch).
//      cols via scalar s_load (readfirstlane'd uniform bounds); packed adds.
__global__ __launch_bounds__(256) void agg1_kernel(const unsigned char* __restrict__ hb8,
                                                   const float* __restrict__ dinv,
                                                   const int2* __restrict__ row2,
                                                   const int* __restrict__ col_src,
                                                   const float* __restrict__ b1,
                                                   const float* __restrict__ W2,
                                                   float* __restrict__ h2p, int n) {
    int wid = threadIdx.x >> 6, lane = threadIdx.x & 63;
    int i = blockIdx.x * 4 + wid;
    if (i >= n) return;
    const int slot = lane >> 4, cl = lane & 15;
    const float di = dinv[i];
    float2v a0, a1, a2, a3;
    {   // self (hprime[i]); only slot 0 contributes
        uint2 r = *(const uint2*)(hb8 + (size_t)i * 128 + cl * 8);
        float w = (slot == 0) ? 1.f : 0.f;
        float2v wv = {w, w};
        a0 = __builtin_amdgcn_cvt_pk_f32_fp8((int)r.x, false) * wv;
        a1 = __builtin_amdgcn_cvt_pk_f32_fp8((int)r.x, true)  * wv;
        a2 = __builtin_amdgcn_cvt_pk_f32_fp8((int)r.y, false) * wv;
        a3 = __builtin_amdgcn_cvt_pk_f32_fp8((int)r.y, true)  * wv;
    }
    const int2 be = row2[i];
    const int beg  = __builtin_amdgcn_readfirstlane(be.x);
    const int endv = __builtin_amdgcn_readfirstlane(be.y);
    for (int e = beg; e < endv; e += 8) {
        int4 c0 = *(const int4*)(col_src + e);       // uniform addr -> s_load
        int4 c1 = *(const int4*)(col_src + e + 4);
        int sx0 = (slot & 1) ? c0.y : c0.x;
        int sy0 = (slot & 1) ? c0.w : c0.z;
        int s0  = (slot & 2) ? sy0 : sx0;
        int sx1 = (slot & 1) ? c1.y : c1.x;
        int sy1 = (slot & 1) ? c1.w : c1.z;
        int s1  = (slot & 2) ? sy1 : sx1;
        uint2 r0 = *(const uint2*)(hb8 + (size_t)s0 * 128 + cl * 8);
        uint2 r1 = *(const uint2*)(hb8 + (size_t)s1 * 128 + cl * 8);
        a0 += __builtin_amdgcn_cvt_pk_f32_fp8((int)r0.x, false);
        a1 += __builtin_amdgcn_cvt_pk_f32_fp8((int)r0.x, true);
        a2 += __builtin_amdgcn_cvt_pk_f32_fp8((int)r0.y, false);
        a3 += __builtin_amdgcn_cvt_pk_f32_fp8((int)r0.y, true);
        a0 += __builtin_amdgcn_cvt_pk_f32_fp8((int)r1.x, false);
        a1 += __builtin_amdgcn_cvt_pk_f32_fp8((int)r1.x, true);
        a2 += __builtin_amdgcn_cvt_pk_f32_fp8((int)r1.y, false);
        a3 += __builtin_amdgcn_cvt_pk_f32_fp8((int)r1.y, true);
    }
    float a[8] = {a0.x, a0.y, a1.x, a1.y, a2.x, a2.y, a3.x, a3.y};
    // fold slots (lane bits 4,5)
    #pragma unroll
    for (int c = 0; c < 8; ++c) {
        a[c] += __shfl_xor(a[c], 16);
        a[c] += __shfl_xor(a[c], 32);
    }
    // bias + relu + W2 (channels 8cl..8cl+7)
    float4 bA = ((const float4*)b1)[2 * cl];
    float4 bB = ((const float4*)b1)[2 * cl + 1];
    float v0 = fmaxf(fmaf(di, a[0], bA.x), 0.f);
    float v1 = fmaxf(fmaf(di, a[1], bA.y), 0.f);
    float v2 = fmaxf(fmaf(di, a[2], bA.z), 0.f);
    float v3 = fmaxf(fmaf(di, a[3], bA.w), 0.f);
    float v4 = fmaxf(fmaf(di, a[4], bB.x), 0.f);
    float v5 = fmaxf(fmaf(di, a[5], bB.y), 0.f);
    float v6 = fmaxf(fmaf(di, a[6], bB.z), 0.f);
    float v7 = fmaxf(fmaf(di, a[7], bB.w), 0.f);
    float4 wA = ((const float4*)W2)[4 * cl];      // rows 8cl,8cl+1
    float4 wB = ((const float4*)W2)[4 * cl + 1];  // rows 8cl+2,8cl+3
    float4 wC = ((const float4*)W2)[4 * cl + 2];
    float4 wD = ((const float4*)W2)[4 * cl + 3];
    float p0 = v0 * wA.x + v1 * wA.z + v2 * wB.x + v3 * wB.z
             + v4 * wC.x + v5 * wC.z + v6 * wD.x + v7 * wD.z;
    float p1 = v0 * wA.y + v1 * wA.w + v2 * wB.y + v3 * wB.w
             + v4 * wC.y + v5 * wC.w + v6 * wD.y + v7 * wD.w;
    p0 += __shfl_xor(p0, 1); p0 += __shfl_xor(p0, 2);
    p0 += __shfl_xor(p0, 4); p0 += __shfl_xor(p0, 8);
    p1 += __shfl_xor(p1, 1); p1 += __shfl_xor(p1, 2);
    p1 += __shfl_xor(p1, 4); p1 += __shfl_xor(p1, 8);
    if (lane == 0) ((float2*)h2p)[i] = make_float2(p0 * di, p1 * di);
}

// ---- layer-2 aggregate + skip: out = di*(sum h2p[src] + h2p[i]) + skip ----
__global__ __launch_bounds__(256) void agg2_kernel(const float* __restrict__ h2p,
                                                   const float* __restrict__ dinv,
                                                   const int2* __restrict__ row2,
                                                   const int* __restrict__ col_src,
                                                   const float* __restrict__ skip,
                                                   float* __restrict__ out, int n) {
    int wid = threadIdx.x >> 6, lane = threadIdx.x & 63;
    int i = blockIdx.x * 4 + wid;
    if (i >= n) return;
    float di = dinv[i];
    float a0 = 0.f, a1 = 0.f;
    const int2 be = row2[i];
    const int beg  = __builtin_amdgcn_readfirstlane(be.x);
    const int endv = __builtin_amdgcn_readfirstlane(be.y);
    for (int e = beg + lane; e < endv; e += 64) {
        int s = col_src[e];
        float2 hs = ((const float2*)h2p)[s];   // pads -> sentinel zeros
        a0 += hs.x;
        a1 += hs.y;
    }
    #pragma unroll
    for (int off = 32; off; off >>= 1) {
        a0 += __shfl_xor(a0, off);
        a1 += __shfl_xor(a1, off);
    }
    if (lane == 0) {
        float2 self = ((const float2*)h2p)[i];
        float2 sk = ((const float2*)skip)[i];
        ((float2*)out)[i] = make_float2(di * (a0 + self.x) + sk.x,
                                        di * (a1 + self.y) + sk.y);
    }
}

extern "C" void kernel_launch(void* const* d_in, const int* in_sizes, int n_in,
                              void* d_out, int out_size, void* d_ws, size_t ws_size,
                              hipStream_t stream) {
    const float* x  = (const float*)d_in[0];
    const int*   ei = (const int*)d_in[1];
    const float* W1 = (const float*)d_in[2];
    const float* b1 = (const float*)d_in[3];
    const float* W2 = (const float*)d_in[4];
    const float* b2 = (const float*)d_in[5];
    const float* Ws = (const float*)d_in[6];
    const float* bs = (const float*)d_in[7];
    float* out = (float*)d_out;

    const int n = in_sizes[0] / IND;        // 100000
    const int E = in_sizes[1] / 2;          // 1600000
    const int NB = (n + 255) >> 8;          // 391 buckets

    char* ws = (char*)d_ws;
    size_t off = 0;
    auto alloc = [&](size_t bytes) { void* p = ws + off; off += (bytes + 255) & ~(size_t)255; return p; };
    int*            flag        = (int*)alloc(256);
    int*            bucket_len  = (int*)alloc((size_t)(MAXNB + 1) * 4);
    unsigned*       slab        = (unsigned*)alloc((size_t)NB * SLAB * 4);
    int2*           row2        = (int2*)alloc((size_t)n * 8);
    float*          dinv        = (float*)alloc((size_t)n * 4);
    int*            col_src     = (int*)alloc((size_t)NB * SLAB * 4);
    unsigned char*  hb8         = (unsigned char*)alloc((size_t)(n + 1) * HID);
    float*          h2p         = (float*)alloc((size_t)(n + 1) * 2 * 4);
    float*          skip        = (float*)alloc((size_t)n * 2 * 4);
    unsigned short* w1t         = (unsigned short*)alloc((size_t)HID * KP * 2);
    (void)ws_size;

    setup_kernel<<<97, 256, 0, stream>>>(W1, w1t, ei, flag, bucket_len, NB);
    partition_kernel<<<(E + 8191) / 8192, 256, 0, stream>>>(ei, flag, bucket_len, slab, E, NB);
    buildb_kernel<<<NB, 256, 0, stream>>>(slab, bucket_len, row2, dinv, col_src, n);

    gemm1_kernel<<<(n + BM - 1) / BM, 256, 0, stream>>>(x, w1t, Ws, bs, b2, dinv, hb8, h2p, skip, n);
    agg1_kernel<<<(n + 3) / 4, 256, 0, stream>>>(hb8, dinv, row2, col_src, b1, W2, h2p, n);
    agg2_kernel<<<(n + 3) / 4, 256, 0, stream>>>(h2p, dinv, row2, col_src, skip, out, n);
}